// Round 8
// baseline (751.993 us; speedup 1.0000x reference)
//
#include <hip/hip_runtime.h>
#include <hip/hip_bf16.h>

#define B 256
#define NELEM 3136          // 64*49 per image
#define TOTAL (B*NELEM)

typedef __attribute__((ext_vector_type(8)))  short bf16x8;
typedef __attribute__((ext_vector_type(4)))  float f32x4;

#define MFMA16(a,b,c) __builtin_amdgcn_mfma_f32_16x16x32_bf16((a),(b),(c),0,0,0)

__device__ __forceinline__ unsigned short f2bf(float f) {
    unsigned u = __float_as_uint(f);
    unsigned r = (u + 0x7fffu + ((u >> 16) & 1u)) >> 16;
    return (unsigned short)r;
}
__device__ __forceinline__ unsigned int f2bf2(float lo, float hi) {
    return (unsigned int)f2bf(lo) | ((unsigned int)f2bf(hi) << 16);
}
__device__ __forceinline__ unsigned int cvtpk(float lo, float hi) {
    unsigned int r;
    asm("v_cvt_pk_bf16_f32 %0, %1, %2" : "=v"(r) : "v"(lo), "v"(hi));
    return r;
}

// lane-tile -> pixel permutation (validated rounds 4-5): each 16-slot tile
// has exactly 2 pixels of each (pa mod 8) residue class -> conflict-free
// conv ds_read_b128. Bijective onto 0..48; slots 49..63 dummies.
__device__ const int d_sigma[64] = {
    6,12,13,19,0,20,1,7,2,8,3,9,4,10,5,11,
    18,24,25,31,26,32,27,33,14,34,15,21,16,22,17,23,
    30,36,37,43,38,44,39,45,40,46,41,47,28,48,29,35,
    42,42,42,42,42,42,42,42,42,42,42,42,42,42,42,42
};

// ---------------------------------------------------------------------------
// Prep: ODE conv weights, 16x16x32 fragment layout (validated r2-r5)
// ---------------------------------------------------------------------------
__global__ __launch_bounds__(256) void prep_afrag_kernel(
    const float* __restrict__ w1, const float* __restrict__ w2,
    short* __restrict__ af1, short* __restrict__ af2)
{
    const int e = blockIdx.x * 256 + threadIdx.x;   // < 36864
    const float* W = blockIdx.y ? w2 : w1;
    short* dst = blockIdx.y ? af2 : af1;
    const int j = e & 7;
    const int lane = (e >> 3) & 63;
    const int kt = (e >> 9) % 18;
    const int mt = (e >> 9) / 18;
    const int m = mt*16 + (lane & 15);
    const int k = kt*32 + ((lane >> 4) & 3)*8 + j;
    const int tap = k >> 6;
    const int ic  = k & 63;
    dst[e] = (short)f2bf(W[m*585 + (ic + 1)*9 + tap]);
}

__global__ __launch_bounds__(256) void prep_stab_kernel(
    const float* __restrict__ w1, const float* __restrict__ w2,
    float* __restrict__ stab1, float* __restrict__ stab2)
{
    const int id = blockIdx.x * 256 + threadIdx.x;
    if (id >= 3136) return;
    const float* W = blockIdx.y ? w2 : w1;
    float* dst = blockIdx.y ? stab2 : stab1;
    const int oc = id / 49, p = id % 49;
    const int py = p / 7, px = p % 7;
    float s = 0.f;
    #pragma unroll
    for (int ky = 0; ky < 3; ++ky) {
        int iy = py - 1 + ky;
        if (iy < 0 || iy > 6) continue;
        #pragma unroll
        for (int kx = 0; kx < 3; ++kx) {
            int ix = px - 1 + kx;
            if (ix < 0 || ix > 6) continue;
            s += W[oc*585 + ky*3 + kx];
        }
    }
    dst[id] = s;
}

__global__ __launch_bounds__(256) void prep_c1frag_kernel(
    const float* __restrict__ w1, short* __restrict__ afc1)
{
    const int e = blockIdx.x * 256 + threadIdx.x;   // < 2048
    const int j = e & 7, lane = (e >> 3) & 63, mtq = e >> 9;
    const int m = mtq*16 + (lane & 15);
    const int k = ((lane >> 4) & 3)*8 + j;
    float v = (k < 27) ? w1[m*27 + k] : 0.f;
    afc1[e] = (short)f2bf(v);
}

__global__ __launch_bounds__(256) void prep_c23frag_kernel(
    const float* __restrict__ w2, const float* __restrict__ w3,
    short* __restrict__ afc2, short* __restrict__ afc3)
{
    const int e = blockIdx.x * 256 + threadIdx.x;   // < 65536
    const float* W = blockIdx.y ? w3 : w2;
    short* dst = blockIdx.y ? afc3 : afc2;
    const int j = e & 7, lane = (e >> 3) & 63, kt = (e >> 9) & 31, mtq = e >> 14;
    const int m = mtq*16 + (lane & 15);
    const int k = kt*32 + ((lane >> 4) & 3)*8 + j;
    const int tap = k >> 6, ic = k & 63;
    dst[e] = (short)f2bf(W[m*1024 + ic*16 + tap]);
}

// ---------------------------------------------------------------------------
// conv1 + GN1 + ReLU fused (unchanged; known good)
// ---------------------------------------------------------------------------
__global__ __launch_bounds__(512, 1) void conv1_fused(
    const float* __restrict__ x, const short* __restrict__ afc1,
    const float* __restrict__ bias,
    const float* __restrict__ g1w, const float* __restrict__ g1b,
    short* __restrict__ h1pad)
{
    __shared__ float xs[3072];
    __shared__ float gnred[128], gnq[128];
    __shared__ float s_mean[32], s_rstd[32];

    const int t = threadIdx.x, b = blockIdx.x;
    const int w = t >> 6, l = t & 63, lhi = (l >> 4) & 3, llo = l & 15;
    const int mt = w & 3, sub = w >> 2;
    const int oc0 = mt*16 + lhi*4;

    for (int i = t; i < 3072; i += 512) xs[i] = x[b*3072 + i];

    bf16x8 afr = *(const bf16x8*)(afc1 + ((size_t)(mt*64 + l))*8);

    int boff[8]; bool bval[8];
    #pragma unroll
    for (int j = 0; j < 8; ++j) {
        int k = lhi*8 + j;
        bval[j] = (k < 27);
        int kk = bval[j] ? k : 0;
        int c = kk / 9, tap = kk % 9;
        boff[j] = c*1024 + (tap/3)*32 + (tap%3);
    }
    f32x4 bia = *(const f32x4*)&bias[oc0];
    __syncthreads();

    f32x4 acc[29];
    float s[4] = {0,0,0,0}, q[4] = {0,0,0,0};
    #pragma unroll
    for (int i = 0; i < 29; ++i) {
        const int nt = sub*29 + i;
        f32x4 a = {0.f,0.f,0.f,0.f};
        if (nt < 57) {
            const int p = nt*16 + llo;
            const int pc = p < 900 ? p : 899;
            const int base = (pc/30)*32 + (pc%30);
            union { bf16x8 v; unsigned u[4]; } bb;
            #pragma unroll
            for (int jj = 0; jj < 4; ++jj) {
                float e0 = bval[2*jj]   ? xs[boff[2*jj]   + base] : 0.f;
                float e1 = bval[2*jj+1] ? xs[boff[2*jj+1] + base] : 0.f;
                bb.u[jj] = f2bf2(e0, e1);
            }
            a = MFMA16(afr, bb.v, a);
            #pragma unroll
            for (int r = 0; r < 4; ++r) {
                a[r] += bia[r];
                if (p < 900) { s[r] += a[r]; q[r] += a[r]*a[r]; }
            }
        }
        acc[i] = a;
    }

    #pragma unroll
    for (int off = 1; off < 16; off <<= 1) {
        #pragma unroll
        for (int r = 0; r < 4; ++r) {
            s[r] += __shfl_xor(s[r], off);
            q[r] += __shfl_xor(q[r], off);
        }
    }
    if (llo == 0) {
        #pragma unroll
        for (int r = 0; r < 4; ++r) {
            gnred[w*16 + lhi*4 + r] = s[r];
            gnq[w*16 + lhi*4 + r]   = q[r];
        }
    }
    __syncthreads();
    if (t < 32) {
        const int oc = t*2;
        const int mtg = oc >> 4, lh = (oc >> 2) & 3, r0 = oc & 3;
        const int i0 = mtg*16 + lh*4 + r0;
        float ss = gnred[i0] + gnred[i0+1] + gnred[i0+64] + gnred[i0+65];
        float qq = gnq[i0]   + gnq[i0+1]   + gnq[i0+64]   + gnq[i0+65];
        float m = ss * (1.f/1800.f);
        float var = qq * (1.f/1800.f) - m*m;
        s_mean[t] = m; s_rstd[t] = rsqrtf(var + 1e-5f);
    }
    __syncthreads();

    const int g0 = oc0 >> 1;
    const float m0 = s_mean[g0],   rs0 = s_rstd[g0];
    const float m1 = s_mean[g0+1], rs1 = s_rstd[g0+1];
    const float w0 = g1w[oc0], w1v = g1w[oc0+1], w2v = g1w[oc0+2], w3v = g1w[oc0+3];
    const float b0 = g1b[oc0], b1v_ = g1b[oc0+1], b2v_ = g1b[oc0+2], b3v_ = g1b[oc0+3];
    char* hb = (char*)h1pad + (size_t)b*131200;

    #pragma unroll
    for (int i = 0; i < 29; ++i) {
        const int nt = sub*29 + i;
        if (nt >= 57) continue;
        const int p = nt*16 + llo;
        if (p >= 900) continue;
        const int pidx = (p/30 + 1)*32 + (p%30 + 1);
        float v0 = fmaxf((acc[i][0]-m0)*rs0*w0  + b0,   0.f);
        float v1 = fmaxf((acc[i][1]-m0)*rs0*w1v + b1v_, 0.f);
        float v2 = fmaxf((acc[i][2]-m1)*rs1*w2v + b2v_, 0.f);
        float v3 = fmaxf((acc[i][3]-m1)*rs1*w3v + b3v_, 0.f);
        uint2 pk; pk.x = f2bf2(v0, v1); pk.y = f2bf2(v2, v3);
        *(uint2*)(hb + (oc0>>3)*16400 + pidx*16 + ((oc0&7)<<1)) = pk;
    }
    for (int u = t; u < 992; u += 512) {
        const int bp = u >> 3, c8 = u & 7;
        int pidx;
        if (bp < 32) pidx = bp;
        else if (bp < 64) pidx = 31*32 + (bp - 32);
        else if (bp < 94) pidx = (bp - 64 + 1)*32;
        else pidx = (bp - 94 + 1)*32 + 31;
        uint4 z; z.x = z.y = z.z = z.w = 0u;
        *(uint4*)(hb + c8*16400 + pidx*16) = z;
    }
}

// ---------------------------------------------------------------------------
// conv2 + GN2 + ReLU fused (unchanged)
// ---------------------------------------------------------------------------
#define CONV2_LDS 132480
__global__ __launch_bounds__(512, 1) void conv2_fused(
    const short* __restrict__ h1pad, const short* __restrict__ afc2,
    const float* __restrict__ bias,
    const float* __restrict__ g2w, const float* __restrict__ g2b,
    short* __restrict__ h2pad)
{
    extern __shared__ char smem[];
    char*  sin    = smem;
    float* gnred  = (float*)(smem + 131200);
    float* gnq    = (float*)(smem + 131712);
    float* s_mean = (float*)(smem + 132224);
    float* s_rstd = (float*)(smem + 132352);

    const int t = threadIdx.x, b = blockIdx.x;
    const int w = t >> 6, l = t & 63, lhi = (l >> 4) & 3, llo = l & 15;
    const int mt = w >> 1, half = w & 1;
    const int oc0 = mt*16 + lhi*4;

    {
        const uint4* src = (const uint4*)((const char*)h1pad + (size_t)b*131200);
        uint4* dst = (uint4*)sin;
        for (int i = t; i < 8200; i += 512) dst[i] = src[i];
    }
    bf16x8 aw[32];
    #pragma unroll
    for (int kt = 0; kt < 32; ++kt)
        aw[kt] = *(const bf16x8*)(afc2 + ((size_t)((mt*32 + kt)*64 + l))*8);
    f32x4 bia = *(const f32x4*)&bias[oc0];
    __syncthreads();

    f32x4 acc[8];
    #pragma unroll
    for (int i = 0; i < 8; ++i) acc[i] = (f32x4){0.f,0.f,0.f,0.f};

    #pragma unroll
    for (int i = 0; i < 8; ++i) {
        const int nt = half*8 + i;
        if (nt > 14) continue;
        const int n = nt*16 + llo;
        const int p = n < 225 ? n : 224;
        const int oy = p/15, ox = p%15;
        #pragma unroll
        for (int kt = 0; kt < 32; ++kt) {
            const int tap = kt >> 1;
            const int ky = tap >> 2, kx = tap & 3;
            const int pidx = (oy*2 + ky)*32 + (ox*2 + kx);
            const int c8 = (kt & 1)*4 + lhi;
            bf16x8 bb = *(const bf16x8*)(sin + c8*16400 + pidx*16);
            acc[i] = MFMA16(aw[kt], bb, acc[i]);
        }
    }

    float s[4] = {0,0,0,0}, q[4] = {0,0,0,0};
    #pragma unroll
    for (int i = 0; i < 8; ++i) {
        const int nt = half*8 + i;
        if (nt > 14) continue;
        const int n = nt*16 + llo;
        #pragma unroll
        for (int r = 0; r < 4; ++r) {
            float v = acc[i][r] + bia[r];
            acc[i][r] = v;
            if (n < 225) { s[r] += v; q[r] += v*v; }
        }
    }
    #pragma unroll
    for (int off = 1; off < 16; off <<= 1) {
        #pragma unroll
        for (int r = 0; r < 4; ++r) {
            s[r] += __shfl_xor(s[r], off);
            q[r] += __shfl_xor(q[r], off);
        }
    }
    if (llo == 0) {
        #pragma unroll
        for (int r = 0; r < 4; ++r) {
            gnred[w*16 + lhi*4 + r] = s[r];
            gnq[w*16 + lhi*4 + r]   = q[r];
        }
    }
    __syncthreads();
    if (t < 32) {
        const int oc = t*2;
        const int mtg = oc >> 4, lh = (oc >> 2) & 3, r0 = oc & 3;
        const int i0 = (mtg*2)*16 + lh*4 + r0;
        float ss = gnred[i0] + gnred[i0+1] + gnred[i0+16] + gnred[i0+17];
        float qq = gnq[i0]   + gnq[i0+1]   + gnq[i0+16]   + gnq[i0+17];
        float m = ss * (1.f/450.f);
        float var = qq * (1.f/450.f) - m*m;
        s_mean[t] = m; s_rstd[t] = rsqrtf(var + 1e-5f);
    }
    __syncthreads();

    const int g0 = oc0 >> 1;
    const float m0 = s_mean[g0],   rs0 = s_rstd[g0];
    const float m1 = s_mean[g0+1], rs1 = s_rstd[g0+1];
    const float w0 = g2w[oc0], w1v = g2w[oc0+1], w2v = g2w[oc0+2], w3v = g2w[oc0+3];
    const float b0 = g2b[oc0], b1v_ = g2b[oc0+1], b2v_ = g2b[oc0+2], b3v_ = g2b[oc0+3];
    char* hb2 = (char*)h2pad + (size_t)b*36992;

    #pragma unroll
    for (int i = 0; i < 8; ++i) {
        const int nt = half*8 + i;
        if (nt > 14) continue;
        const int n = nt*16 + llo;
        if (n >= 225) continue;
        const int pidx = (n/15 + 1)*17 + (n%15 + 1);
        float v0 = fmaxf((acc[i][0]-m0)*rs0*w0  + b0,   0.f);
        float v1 = fmaxf((acc[i][1]-m0)*rs0*w1v + b1v_, 0.f);
        float v2 = fmaxf((acc[i][2]-m1)*rs1*w2v + b2v_, 0.f);
        float v3 = fmaxf((acc[i][3]-m1)*rs1*w3v + b3v_, 0.f);
        uint2 pk; pk.x = f2bf2(v0, v1); pk.y = f2bf2(v2, v3);
        *(uint2*)(hb2 + (oc0>>3)*4624 + pidx*16 + ((oc0&7)<<1)) = pk;
    }
    if (t < 512) {
        const int bp = t >> 3, c8 = t & 7;
        int pidx;
        if (bp < 17) pidx = bp;
        else if (bp < 34) pidx = 16*17 + (bp - 17);
        else if (bp < 49) pidx = (bp - 34 + 1)*17;
        else pidx = (bp - 49 + 1)*17 + 16;
        uint4 z; z.x = z.y = z.z = z.w = 0u;
        *(uint4*)(hb2 + c8*4624 + pidx*16) = z;
    }
}

// ---------------------------------------------------------------------------
// conv3 MFMA -> y fp32 (unchanged)
// ---------------------------------------------------------------------------
__global__ __launch_bounds__(512, 1) void conv3_mfma(
    const short* __restrict__ h2pad, const short* __restrict__ afc3,
    const float* __restrict__ bias, float* __restrict__ y)
{
    __shared__ __align__(16) char sin[36992];
    const int t = threadIdx.x, b = blockIdx.x;
    const int w = t >> 6, l = t & 63, lhi = (l >> 4) & 3, llo = l & 15;
    const int mt = w >> 1, half = w & 1;
    const int oc0 = mt*16 + lhi*4;

    {
        const uint4* src = (const uint4*)((const char*)h2pad + (size_t)b*36992);
        uint4* dst = (uint4*)sin;
        for (int i = t; i < 2312; i += 512) dst[i] = src[i];
    }
    bf16x8 aw[32];
    #pragma unroll
    for (int kt = 0; kt < 32; ++kt)
        aw[kt] = *(const bf16x8*)(afc3 + ((size_t)((mt*32 + kt)*64 + l))*8);
    f32x4 bia = *(const f32x4*)&bias[oc0];
    __syncthreads();

    f32x4 acc[2];
    acc[0] = (f32x4){0.f,0.f,0.f,0.f};
    acc[1] = (f32x4){0.f,0.f,0.f,0.f};
    #pragma unroll
    for (int i = 0; i < 2; ++i) {
        const int nt = half*2 + i;
        const int n = nt*16 + llo;
        const int p = n < 49 ? n : 48;
        const int oy = p/7, ox = p%7;
        #pragma unroll
        for (int kt = 0; kt < 32; ++kt) {
            const int tap = kt >> 1;
            const int ky = tap >> 2, kx = tap & 3;
            const int pidx = (oy*2 + ky)*17 + (ox*2 + kx);
            const int c8 = (kt & 1)*4 + lhi;
            bf16x8 bb = *(const bf16x8*)(sin + c8*4624 + pidx*16);
            acc[i] = MFMA16(aw[kt], bb, acc[i]);
        }
    }
    #pragma unroll
    for (int i = 0; i < 2; ++i) {
        const int n = (half*2 + i)*16 + llo;
        if (n < 49) {
            #pragma unroll
            for (int r = 0; r < 4; ++r)
                y[(size_t)b*NELEM + (oc0 + r)*49 + n] = acc[i][r] + bia[r];
        }
    }
}

// ---------------------------------------------------------------------------
// ODE + head: 512 thr, 8 waves = (ms 0..1) x (np 0..3). Each wave: 2 M-strips
// (aw[2][18], reloaded per conv) x ONE 16-slot pixel tile. 1 B-read -> 2
// MFMAs; conv B-reads/stage = 288 (vs r4's 576). Round-4 skeleton + numerics.
// ---------------------------------------------------------------------------
#define SGRP 104
#define KSTR 3328
#define ACT_C8 1296
#define ODE_LDS 117248
#define P_B1 0
#define P_B2 64
#define P_GWB 128
#define P_GBB 192
#define P_GWC 256
#define P_GBC 320
#define P_OAW 384
#define P_OAB 448
__global__ __launch_bounds__(512, 2) void ode_head(
    const float* __restrict__ yin,
    const short* __restrict__ af1, const short* __restrict__ af2,
    const float* __restrict__ stab1, const float* __restrict__ stab2,
    const float* __restrict__ b1v, const float* __restrict__ b2v,
    const float* __restrict__ oaw, const float* __restrict__ oab,
    const float* __restrict__ obw, const float* __restrict__ obb,
    const float* __restrict__ ocw, const float* __restrict__ ocb,
    const float* __restrict__ g3w, const float* __restrict__ g3b,
    const float* __restrict__ linw, const float* __restrict__ linb,
    float* __restrict__ out)
{
    extern __shared__ char smem[];
    float* y_l   = (float*)smem;                   // [32][104]
    float* kbuf  = (float*)(smem + 13312);         // 6 x [32][104]
    char*  act0  = smem + 93184;                   // [8][81][16]
    char*  act1  = smem + 103552;
    float* prm   = (float*)(smem + 113920);        // 512 floats
    float* gnred = (float*)(smem + 115968);        // 256 floats
    float* s_cm  = (float*)(smem + 116992);        // 64

    const int t = threadIdx.x, b = blockIdx.x;
    const int w = t >> 6, l = t & 63, lhi = (l >> 4) & 3, llo = l & 15;
    const int g16 = t >> 4, sub = t & 15;

    // conv geometry: wave (ms, np)
    const int ms = w >> 2, np = w & 3;
    const int n  = np*16 + llo;
    const bool vpx = n < 49;
    const int px = d_sigma[n];
    const int pa = (px/7 + 1)*9 + (px%7 + 1);
    const int mt0 = 2*ms, mt1 = 2*ms + 1;

    // ---- init ----
    for (int u = t; u < 3136; u += 512) {
        const int g = u / 98, e = u - g*98;
        y_l[g*SGRP + e] = yin[(size_t)b*NELEM + u];
    }
    for (int i = t; i < 5184; i += 512) ((unsigned*)act0)[i] = 0u;   // both act buffers
    if (t < 64) {
        prm[P_B1  + t] = b1v[t]; prm[P_B2  + t] = b2v[t];
        prm[P_GWB + t] = obw[t]; prm[P_GBB + t] = obb[t];
        prm[P_GWC + t] = ocw[t]; prm[P_GBC + t] = ocb[t];
        prm[P_OAW + t] = oaw[t]; prm[P_OAB + t] = oab[t];
    }
    // t-channel stab values for this thread's pixel (persist in regs)
    float st1[2][4], st2[2][4];
    #pragma unroll
    for (int s = 0; s < 2; ++s) {
        const int ocs = (2*ms + s)*16 + lhi*4;
        #pragma unroll
        for (int r = 0; r < 4; ++r) {
            st1[s][r] = stab1[(ocs + r)*49 + px];
            st2[s][r] = stab2[(ocs + r)*49 + px];
        }
    }
    __syncthreads();

    const float hf  = (float)(1.0/6.0);
    const float C10 = (float)((1.0/6.0)*(1.0/5.0));
    const float C20 = (float)((1.0/6.0)*(3.0/40.0)),  C21 = (float)((1.0/6.0)*(9.0/40.0));
    const float C30 = (float)((1.0/6.0)*(44.0/45.0)), C31 = (float)((1.0/6.0)*(-56.0/15.0)), C32 = (float)((1.0/6.0)*(32.0/9.0));
    const float C40 = (float)((1.0/6.0)*(19372.0/6561.0)), C41 = (float)((1.0/6.0)*(-25360.0/2187.0)),
                C42 = (float)((1.0/6.0)*(64448.0/6561.0)), C43 = (float)((1.0/6.0)*(-212.0/729.0));
    const float C50 = (float)((1.0/6.0)*(9017.0/3168.0)), C51 = (float)((1.0/6.0)*(-355.0/33.0)),
                C52 = (float)((1.0/6.0)*(46732.0/5247.0)), C53 = (float)((1.0/6.0)*(49.0/176.0)),
                C54 = (float)((1.0/6.0)*(-5103.0/18656.0));
    const float B0 = (float)((1.0/6.0)*(35.0/384.0)), B2c = (float)((1.0/6.0)*(500.0/1113.0)),
                B3c = (float)((1.0/6.0)*(125.0/192.0)), B4c = (float)((1.0/6.0)*(-2187.0/6784.0)),
                B5c = (float)((1.0/6.0)*(11.0/84.0));

    for (int step = 0; step < 6; ++step) {
        const float t0 = (float)step * hf;
        for (int stage = 0; stage < 6; ++stage) {
            float cA=0.f, cB=0.f, cC=0.f, cD=0.f, cE=0.f, tf=0.f;
            if (stage == 1)      { cA=C10; tf = 0.2f; }
            else if (stage == 2) { cA=C20; cB=C21; tf = 0.3f; }
            else if (stage == 3) { cA=C30; cB=C31; cC=C32; tf = 0.8f; }
            else if (stage == 4) { cA=C40; cB=C41; cC=C42; cD=C43; tf = (float)(8.0/9.0); }
            else if (stage == 5) { cA=C50; cB=C51; cC=C52; cD=C53; cE=C54; tf = 1.f; }
            const float tval = t0 + hf*tf;

            // issue conv1 A-strip loads early (L2-hot; hidden under P1)
            bf16x8 aw[2][18];
            #pragma unroll
            for (int kt = 0; kt < 18; ++kt) {
                aw[0][kt] = *(const bf16x8*)(af1 + ((size_t)(mt0*18 + kt)*64 + l)*8);
                aw[1][kt] = *(const bf16x8*)(af1 + ((size_t)(mt1*18 + kt)*64 + l)*8);
            }

            // ---- phase 1: combine + GN_oa (16 thr/group) + act0 write ----
            {
                const float* Yg = y_l + g16*SGRP;
                const float* Kg = kbuf + g16*SGRP;
                const int e0 = 4*sub;
                const int n1 = (sub < 8) ? 4 : ((sub == 8) ? 2 : 0);
                const int e1 = 64 + 4*sub;

                f32x4 va, vb = {0.f,0.f,0.f,0.f};
                {
                    f32x4 xv = *(const f32x4*)(Yg + e0);
                    if (stage > 0) xv += cA * *(const f32x4*)(Kg + 0*KSTR + e0);
                    if (stage > 1) xv += cB * *(const f32x4*)(Kg + 1*KSTR + e0);
                    if (stage > 2) xv += cC * *(const f32x4*)(Kg + 2*KSTR + e0);
                    if (stage > 3) xv += cD * *(const f32x4*)(Kg + 3*KSTR + e0);
                    if (stage > 4) xv += cE * *(const f32x4*)(Kg + 4*KSTR + e0);
                    va = xv;
                }
                if (n1 == 4) {
                    f32x4 xv = *(const f32x4*)(Yg + e1);
                    if (stage > 0) xv += cA * *(const f32x4*)(Kg + 0*KSTR + e1);
                    if (stage > 1) xv += cB * *(const f32x4*)(Kg + 1*KSTR + e1);
                    if (stage > 2) xv += cC * *(const f32x4*)(Kg + 2*KSTR + e1);
                    if (stage > 3) xv += cD * *(const f32x4*)(Kg + 3*KSTR + e1);
                    if (stage > 4) xv += cE * *(const f32x4*)(Kg + 4*KSTR + e1);
                    vb = xv;
                } else if (n1 == 2) {
                    float x0 = Yg[96], x1 = Yg[97];
                    if (stage > 0) { x0 = fmaf(cA, Kg[0*KSTR+96], x0); x1 = fmaf(cA, Kg[0*KSTR+97], x1); }
                    if (stage > 1) { x0 = fmaf(cB, Kg[1*KSTR+96], x0); x1 = fmaf(cB, Kg[1*KSTR+97], x1); }
                    if (stage > 2) { x0 = fmaf(cC, Kg[2*KSTR+96], x0); x1 = fmaf(cC, Kg[2*KSTR+97], x1); }
                    if (stage > 3) { x0 = fmaf(cD, Kg[3*KSTR+96], x0); x1 = fmaf(cD, Kg[3*KSTR+97], x1); }
                    if (stage > 4) { x0 = fmaf(cE, Kg[4*KSTR+96], x0); x1 = fmaf(cE, Kg[4*KSTR+97], x1); }
                    vb[0] = x0; vb[1] = x1;
                }

                float s = va[0]+va[1]+va[2]+va[3];
                float q = va[0]*va[0]+va[1]*va[1]+va[2]*va[2]+va[3]*va[3];
                if (n1 >= 2) { s += vb[0]+vb[1]; q += vb[0]*vb[0]+vb[1]*vb[1]; }
                if (n1 == 4) { s += vb[2]+vb[3]; q += vb[2]*vb[2]+vb[3]*vb[3]; }
                s += __shfl_xor(s, 1); q += __shfl_xor(q, 1);
                s += __shfl_xor(s, 2); q += __shfl_xor(q, 2);
                s += __shfl_xor(s, 4); q += __shfl_xor(q, 4);
                s += __shfl_xor(s, 8); q += __shfl_xor(q, 8);
                const float m = s * (1.f/98.f);
                const float rs = rsqrtf(q * (1.f/98.f) - m*m + 1e-5f);
                const float w0 = prm[P_OAW + 2*g16], w1c = prm[P_OAW + 2*g16 + 1];
                const float c0 = prm[P_OAB + 2*g16], c1c = prm[P_OAB + 2*g16 + 1];

                #pragma unroll
                for (int j2 = 0; j2 < 4; ++j2) {
                    const int e = e0 + j2;
                    const int odd = e >= 49 ? 1 : 0;
                    const int ch = 2*g16 + odd;
                    const int p = e - 49*odd;
                    float nv = fmaxf((va[j2] - m)*rs*(odd ? w1c : w0) + (odd ? c1c : c0), 0.f);
                    const int pw = (p/7 + 1)*9 + (p%7) + 1;
                    *(unsigned short*)(act0 + (ch>>3)*ACT_C8 + pw*16 + ((ch&7)<<1)) = f2bf(nv);
                }
                for (int j2 = 0; j2 < n1; ++j2) {
                    const int e = e1 + j2;
                    const int odd = e >= 49 ? 1 : 0;
                    const int ch = 2*g16 + odd;
                    const int p = e - 49*odd;
                    float nv = fmaxf((vb[j2] - m)*rs*(odd ? w1c : w0) + (odd ? c1c : c0), 0.f);
                    const int pw = (p/7 + 1)*9 + (p%7) + 1;
                    *(unsigned short*)(act0 + (ch>>3)*ACT_C8 + pw*16 + ((ch&7)<<1)) = f2bf(nv);
                }
            }
            __syncthreads();   // S1: act0 ready

            // ---- conv1: 18 B-reads -> 36 MFMAs (dual strip) ----
            float v0[2][4];
            {
                f32x4 a0 = {0.f,0.f,0.f,0.f}, a1 = {0.f,0.f,0.f,0.f};
                #pragma unroll
                for (int kt = 0; kt < 18; ++kt) {
                    const int tap = kt >> 1;
                    const int dB = ((tap/3 - 1)*9 + (tap%3 - 1))*16;
                    const int cb = ((kt & 1)*4 + lhi)*ACT_C8;
                    bf16x8 bb = *(const bf16x8*)(act0 + cb + pa*16 + dB);
                    a0 = MFMA16(aw[0][kt], bb, a0);
                    a1 = MFMA16(aw[1][kt], bb, a1);
                }
                // prefetch conv2 A-strips (hidden under GN)
                #pragma unroll
                for (int kt = 0; kt < 18; ++kt) {
                    aw[0][kt] = *(const bf16x8*)(af2 + ((size_t)(mt0*18 + kt)*64 + l)*8);
                    aw[1][kt] = *(const bf16x8*)(af2 + ((size_t)(mt1*18 + kt)*64 + l)*8);
                }
                #pragma unroll
                for (int s = 0; s < 2; ++s) {
                    const int ocs = (2*ms + s)*16 + lhi*4;
                    f32x4 bia = *(const f32x4*)&prm[P_B1 + ocs];
                    #pragma unroll
                    for (int r = 0; r < 4; ++r)
                        v0[s][r] = (s ? a1[r] : a0[r]) + bia[r] + tval * st1[s][r];
                }
            }
            // GN_ob stats: in-wave 16-lane reduce + cross-np gnred
            #pragma unroll
            for (int s = 0; s < 2; ++s) {
                float s0=0.f,q0=0.f,s1=0.f,q1=0.f;
                if (vpx) {
                    s0 = v0[s][0]+v0[s][1]; q0 = v0[s][0]*v0[s][0]+v0[s][1]*v0[s][1];
                    s1 = v0[s][2]+v0[s][3]; q1 = v0[s][2]*v0[s][2]+v0[s][3]*v0[s][3];
                }
                s0 += __shfl_xor(s0,1); q0 += __shfl_xor(q0,1); s1 += __shfl_xor(s1,1); q1 += __shfl_xor(q1,1);
                s0 += __shfl_xor(s0,2); q0 += __shfl_xor(q0,2); s1 += __shfl_xor(s1,2); q1 += __shfl_xor(q1,2);
                s0 += __shfl_xor(s0,4); q0 += __shfl_xor(q0,4); s1 += __shfl_xor(s1,4); q1 += __shfl_xor(q1,4);
                s0 += __shfl_xor(s0,8); q0 += __shfl_xor(q0,8); s1 += __shfl_xor(s1,8); q1 += __shfl_xor(q1,8);
                if (llo == 0) {
                    const int p0 = (2*ms + s)*8 + lhi*2;
                    gnred[p0*8 + np*2]         = s0;
                    gnred[p0*8 + np*2 + 1]     = q0;
                    gnred[(p0+1)*8 + np*2]     = s1;
                    gnred[(p0+1)*8 + np*2 + 1] = q1;
                }
            }
            __syncthreads();   // S2: gnred ready

            // GN_ob apply + ReLU -> act1
            #pragma unroll
            for (int s = 0; s < 2; ++s) {
                const int ocs = (2*ms + s)*16 + lhi*4;
                const int p0 = ocs >> 1;
                const float sg0 = gnred[p0*8]+gnred[p0*8+2]+gnred[p0*8+4]+gnred[p0*8+6];
                const float qg0 = gnred[p0*8+1]+gnred[p0*8+3]+gnred[p0*8+5]+gnred[p0*8+7];
                const float sg1 = gnred[(p0+1)*8]+gnred[(p0+1)*8+2]+gnred[(p0+1)*8+4]+gnred[(p0+1)*8+6];
                const float qg1 = gnred[(p0+1)*8+1]+gnred[(p0+1)*8+3]+gnred[(p0+1)*8+5]+gnred[(p0+1)*8+7];
                const float m0 = sg0*(1.f/98.f);
                const float r0 = rsqrtf(qg0*(1.f/98.f) - m0*m0 + 1e-5f);
                const float m1 = sg1*(1.f/98.f);
                const float r1 = rsqrtf(qg1*(1.f/98.f) - m1*m1 + 1e-5f);
                f32x4 gw = *(const f32x4*)&prm[P_GWB + ocs];
                f32x4 gc = *(const f32x4*)&prm[P_GBB + ocs];
                if (vpx) {
                    float x0 = fmaxf((v0[s][0]-m0)*r0*gw[0]+gc[0], 0.f);
                    float x1 = fmaxf((v0[s][1]-m0)*r0*gw[1]+gc[1], 0.f);
                    float x2 = fmaxf((v0[s][2]-m1)*r1*gw[2]+gc[2], 0.f);
                    float x3 = fmaxf((v0[s][3]-m1)*r1*gw[3]+gc[3], 0.f);
                    uint2 pk; pk.x = cvtpk(x0, x1); pk.y = cvtpk(x2, x3);
                    *(uint2*)(act1 + (ocs>>3)*ACT_C8 + pa*16 + ((ocs&7)<<1)) = pk;
                }
            }
            __syncthreads();   // S3: act1 ready

            // ---- conv2: 18 B-reads -> 36 MFMAs ----
            {
                f32x4 a0 = {0.f,0.f,0.f,0.f}, a1 = {0.f,0.f,0.f,0.f};
                #pragma unroll
                for (int kt = 0; kt < 18; ++kt) {
                    const int tap = kt >> 1;
                    const int dB = ((tap/3 - 1)*9 + (tap%3 - 1))*16;
                    const int cb = ((kt & 1)*4 + lhi)*ACT_C8;
                    bf16x8 bb = *(const bf16x8*)(act1 + cb + pa*16 + dB);
                    a0 = MFMA16(aw[0][kt], bb, a0);
                    a1 = MFMA16(aw[1][kt], bb, a1);
                }
                #pragma unroll
                for (int s = 0; s < 2; ++s) {
                    const int ocs = (2*ms + s)*16 + lhi*4;
                    f32x4 bia = *(const f32x4*)&prm[P_B2 + ocs];
                    #pragma unroll
                    for (int r = 0; r < 4; ++r)
                        v0[s][r] = (s ? a1[r] : a0[r]) + bia[r] + tval * st2[s][r];
                }
            }
            #pragma unroll
            for (int s = 0; s < 2; ++s) {
                float s0=0.f,q0=0.f,s1=0.f,q1=0.f;
                if (vpx) {
                    s0 = v0[s][0]+v0[s][1]; q0 = v0[s][0]*v0[s][0]+v0[s][1]*v0[s][1];
                    s1 = v0[s][2]+v0[s][3]; q1 = v0[s][2]*v0[s][2]+v0[s][3]*v0[s][3];
                }
                s0 += __shfl_xor(s0,1); q0 += __shfl_xor(q0,1); s1 += __shfl_xor(s1,1); q1 += __shfl_xor(q1,1);
                s0 += __shfl_xor(s0,2); q0 += __shfl_xor(q0,2); s1 += __shfl_xor(s1,2); q1 += __shfl_xor(q1,2);
                s0 += __shfl_xor(s0,4); q0 += __shfl_xor(q0,4); s1 += __shfl_xor(s1,4); q1 += __shfl_xor(q1,4);
                s0 += __shfl_xor(s0,8); q0 += __shfl_xor(q0,8); s1 += __shfl_xor(s1,8); q1 += __shfl_xor(q1,8);
                if (llo == 0) {
                    const int p0 = (2*ms + s)*8 + lhi*2;
                    gnred[p0*8 + np*2]         = s0;
                    gnred[p0*8 + np*2 + 1]     = q0;
                    gnred[(p0+1)*8 + np*2]     = s1;
                    gnred[(p0+1)*8 + np*2 + 1] = q1;
                }
            }
            __syncthreads();   // S4: gnred ready

            // GN_oc apply (no relu) -> kbuf[stage]
            {
                float* kd = kbuf + stage*KSTR;
                #pragma unroll
                for (int s = 0; s < 2; ++s) {
                    const int ocs = (2*ms + s)*16 + lhi*4;
                    const int p0 = ocs >> 1;
                    const float sg0 = gnred[p0*8]+gnred[p0*8+2]+gnred[p0*8+4]+gnred[p0*8+6];
                    const float qg0 = gnred[p0*8+1]+gnred[p0*8+3]+gnred[p0*8+5]+gnred[p0*8+7];
                    const float sg1 = gnred[(p0+1)*8]+gnred[(p0+1)*8+2]+gnred[(p0+1)*8+4]+gnred[(p0+1)*8+6];
                    const float qg1 = gnred[(p0+1)*8+1]+gnred[(p0+1)*8+3]+gnred[(p0+1)*8+5]+gnred[(p0+1)*8+7];
                    const float m0 = sg0*(1.f/98.f);
                    const float r0 = rsqrtf(qg0*(1.f/98.f) - m0*m0 + 1e-5f);
                    const float m1 = sg1*(1.f/98.f);
                    const float r1 = rsqrtf(qg1*(1.f/98.f) - m1*m1 + 1e-5f);
                    f32x4 gw = *(const f32x4*)&prm[P_GWC + ocs];
                    f32x4 gc = *(const f32x4*)&prm[P_GBC + ocs];
                    if (vpx) {
                        kd[p0*SGRP + px]          = (v0[s][0]-m0)*r0*gw[0]+gc[0];
                        kd[p0*SGRP + 49 + px]     = (v0[s][1]-m0)*r0*gw[1]+gc[1];
                        kd[(p0+1)*SGRP + px]      = (v0[s][2]-m1)*r1*gw[2]+gc[2];
                        kd[(p0+1)*SGRP + 49 + px] = (v0[s][3]-m1)*r1*gw[3]+gc[3];
                    }
                }
            }
            __syncthreads();   // S5: k ready

            if (stage == 5) {
                float* Yg = y_l + g16*SGRP;
                const float* Kg = kbuf + g16*SGRP;
                const int e0 = 4*sub;
                {
                    f32x4 v = *(const f32x4*)(Yg + e0);
                    v += B0  * *(const f32x4*)(Kg + 0*KSTR + e0);
                    v += B2c * *(const f32x4*)(Kg + 2*KSTR + e0);
                    v += B3c * *(const f32x4*)(Kg + 3*KSTR + e0);
                    v += B4c * *(const f32x4*)(Kg + 4*KSTR + e0);
                    v += B5c * *(const f32x4*)(Kg + 5*KSTR + e0);
                    *(f32x4*)(Yg + e0) = v;
                }
                if (sub < 8) {
                    const int e1 = 64 + 4*sub;
                    f32x4 v = *(const f32x4*)(Yg + e1);
                    v += B0  * *(const f32x4*)(Kg + 0*KSTR + e1);
                    v += B2c * *(const f32x4*)(Kg + 2*KSTR + e1);
                    v += B3c * *(const f32x4*)(Kg + 3*KSTR + e1);
                    v += B4c * *(const f32x4*)(Kg + 4*KSTR + e1);
                    v += B5c * *(const f32x4*)(Kg + 5*KSTR + e1);
                    *(f32x4*)(Yg + e1) = v;
                } else if (sub == 8) {
                    #pragma unroll
                    for (int j2 = 0; j2 < 2; ++j2) {
                        const int e = 96 + j2;
                        float v = Yg[e];
                        v = fmaf(B0,  Kg[0*KSTR+e], v);
                        v = fmaf(B2c, Kg[2*KSTR+e], v);
                        v = fmaf(B3c, Kg[3*KSTR+e], v);
                        v = fmaf(B4c, Kg[4*KSTR+e], v);
                        v = fmaf(B5c, Kg[5*KSTR+e], v);
                        Yg[e] = v;
                    }
                }
                __syncthreads();   // S6: y updated
            }
        }
    }

    // ---- head: GN(g3)+ReLU -> spatial mean -> linear ----
    float* hstat = kbuf;   // kbuf dead now
    {
        float s = 0.f, q = 0.f;
        const float* Yg = y_l + g16*SGRP;
        for (int e = sub; e < 98; e += 16) {
            float v = Yg[e];
            s += v; q += v*v;
        }
        s += __shfl_xor(s,1); q += __shfl_xor(q,1);
        s += __shfl_xor(s,2); q += __shfl_xor(q,2);
        s += __shfl_xor(s,4); q += __shfl_xor(q,4);
        s += __shfl_xor(s,8); q += __shfl_xor(q,8);
        if (sub == 0) {
            float m = s * (1.f/98.f);
            float var = q * (1.f/98.f) - m*m;
            hstat[g16] = m; hstat[32 + g16] = rsqrtf(var + 1e-5f);
        }
    }
    __syncthreads();
    if (t < 64) {
        const int ch = t, g = ch >> 1;
        const float m = hstat[g], r = hstat[32 + g];
        const float ww = g3w[ch], bb = g3b[ch];
        const float* Yc = y_l + g*SGRP + (ch & 1)*49;
        float sum = 0.f;
        for (int p = 0; p < 49; ++p) {
            float v = (Yc[p] - m)*r*ww + bb;
            sum += fmaxf(v, 0.f);
        }
        s_cm[ch] = sum * (1.f/49.f);
    }
    __syncthreads();
    if (t < 10) {
        float a = linb[t];
        for (int c = 0; c < 64; ++c) a = fmaf(s_cm[c], linw[t*64 + c], a);
        out[b*10 + t] = a;
    }
}

// ---------------------------------------------------------------------------
// Host launch
// ---------------------------------------------------------------------------
extern "C" void kernel_launch(void* const* d_in, const int* in_sizes, int n_in,
                              void* d_out, int out_size, void* d_ws, size_t ws_size,
                              hipStream_t stream)
{
    const float* x      = (const float*)d_in[0];
    const float* c1_w   = (const float*)d_in[1];
    const float* c1_b   = (const float*)d_in[2];
    const float* g1_w   = (const float*)d_in[3];
    const float* g1_b   = (const float*)d_in[4];
    const float* c2_w   = (const float*)d_in[5];
    const float* c2_b   = (const float*)d_in[6];
    const float* g2_w   = (const float*)d_in[7];
    const float* g2_b   = (const float*)d_in[8];
    const float* c3_w   = (const float*)d_in[9];
    const float* c3_b   = (const float*)d_in[10];
    const float* oa_w   = (const float*)d_in[11];
    const float* oa_b   = (const float*)d_in[12];
    const float* occ1_w = (const float*)d_in[13];
    const float* occ1_b = (const float*)d_in[14];
    const float* ob_w   = (const float*)d_in[15];
    const float* ob_b   = (const float*)d_in[16];
    const float* occ2_w = (const float*)d_in[17];
    const float* occ2_b = (const float*)d_in[18];
    const float* oc_w   = (const float*)d_in[19];
    const float* oc_b   = (const float*)d_in[20];
    const float* g3_w   = (const float*)d_in[21];
    const float* g3_b   = (const float*)d_in[22];
    const float* lin_w  = (const float*)d_in[23];
    const float* lin_b  = (const float*)d_in[24];
    float* out = (float*)d_out;

    float* ws = (float*)d_ws;
    size_t off = 0;
    float* y     = ws + off; off += 802816;
    float* stab1 = ws + off; off += 3136;
    float* stab2 = ws + off; off += 3136;
    short* af1   = (short*)(ws + off); off += 18432;    // 36864 shorts
    short* af2   = (short*)(ws + off); off += 18432;
    short* afc1  = (short*)(ws + off); off += 1024;     // 2048 shorts
    short* afc2  = (short*)(ws + off); off += 32768;    // 65536 shorts
    short* afc3  = (short*)(ws + off); off += 32768;
    short* h1pad = (short*)(ws + off); off += 8396800;  // 256*65600 shorts
    short* h2pad = (short*)(ws + off); off += 2367488;  // 256*18496 shorts

    // prep (weights constant per launch)
    prep_afrag_kernel<<<dim3(144, 2), 256, 0, stream>>>(occ1_w, occ2_w, af1, af2);
    prep_stab_kernel<<<dim3(13, 2), 256, 0, stream>>>(occ1_w, occ2_w, stab1, stab2);
    prep_c1frag_kernel<<<8, 256, 0, stream>>>(c1_w, afc1);
    prep_c23frag_kernel<<<dim3(256, 2), 256, 0, stream>>>(c2_w, c3_w, afc2, afc3);

    // preamble CNN (fused, per-image MFMA)
    conv1_fused<<<B, 512, 0, stream>>>(x, afc1, c1_b, g1_w, g1_b, h1pad);
    conv2_fused<<<B, 512, CONV2_LDS, stream>>>(h1pad, afc2, c2_b, g2_w, g2_b, h2pad);
    conv3_mfma<<<B, 512, 0, stream>>>(h2pad, afc3, c3_b, y);

    // full ODE + head, one launch
    ode_head<<<B, 512, ODE_LDS, stream>>>(y, af1, af2, stab1, stab2,
        occ1_b, occ2_b, oa_w, oa_b, ob_w, ob_b, oc_w, oc_b,
        g3_w, g3_b, lin_w, lin_b, out);
}

// Round 9
// 648.924 us; speedup vs baseline: 1.1588x; 1.1588x over previous
//
#include <hip/hip_runtime.h>
#include <hip/hip_bf16.h>

#define B 256
#define NELEM 3136          // 64*49 per image
#define TOTAL (B*NELEM)

typedef __attribute__((ext_vector_type(8))) short bf16x8;
typedef __attribute__((ext_vector_type(4))) float f32x4;

#define MFMA16(a,b,c) __builtin_amdgcn_mfma_f32_16x16x32_bf16((a),(b),(c),0,0,0)

__device__ __forceinline__ unsigned short f2bf(float f) {
    unsigned u = __float_as_uint(f);
    unsigned r = (u + 0x7fffu + ((u >> 16) & 1u)) >> 16;
    return (unsigned short)r;
}
__device__ __forceinline__ unsigned int f2bf2(float lo, float hi) {
    return (unsigned int)f2bf(lo) | ((unsigned int)f2bf(hi) << 16);
}
__device__ __forceinline__ unsigned int cvtpk(float lo, float hi) {
    unsigned int r;
    asm("v_cvt_pk_bf16_f32 %0, %1, %2" : "=v"(r) : "v"(lo), "v"(hi));
    return r;
}
__device__ __forceinline__ float bf2f(unsigned short h) {
    return __uint_as_float(((unsigned)h) << 16);
}
// 4 packed bf16 (8B aligned) -> f32x4
__device__ __forceinline__ f32x4 ld_k4(const short* p) {
    uint2 u = *(const uint2*)p;
    f32x4 r;
    r[0] = __uint_as_float(u.x << 16);
    r[1] = __uint_as_float(u.x & 0xffff0000u);
    r[2] = __uint_as_float(u.y << 16);
    r[3] = __uint_as_float(u.y & 0xffff0000u);
    return r;
}

// lane-tile -> pixel permutation: each 16-lane tile has exactly 2 pixels of
// each (pa mod 8) residue class -> conflict-free conv ds_read_b128.
__device__ const int d_sigma[64] = {
    6,12,13,19,0,20,1,7,2,8,3,9,4,10,5,11,
    18,24,25,31,26,32,27,33,14,34,15,21,16,22,17,23,
    30,36,37,43,38,44,39,45,40,46,41,47,28,48,29,35,
    42,42,42,42,42,42,42,42,42,42,42,42,42,42,42,42
};

// ---------------------------------------------------------------------------
// Weight-fragment prep kernels (unchanged, validated)
// ---------------------------------------------------------------------------
__global__ __launch_bounds__(256) void prep_afrag_kernel(
    const float* __restrict__ w1, const float* __restrict__ w2,
    short* __restrict__ af1, short* __restrict__ af2)
{
    const int e = blockIdx.x * 256 + threadIdx.x;   // < 36864
    const float* W = blockIdx.y ? w2 : w1;
    short* dst = blockIdx.y ? af2 : af1;
    const int j = e & 7;
    const int lane = (e >> 3) & 63;
    const int kt = (e >> 9) % 18;
    const int mt = (e >> 9) / 18;
    const int m = mt*16 + (lane & 15);
    const int k = kt*32 + ((lane >> 4) & 3)*8 + j;
    const int tap = k >> 6;
    const int ic  = k & 63;
    dst[e] = (short)f2bf(W[m*585 + (ic + 1)*9 + tap]);
}

__global__ __launch_bounds__(256) void prep_stab_kernel(
    const float* __restrict__ w1, const float* __restrict__ w2,
    float* __restrict__ stab1, float* __restrict__ stab2)
{
    const int id = blockIdx.x * 256 + threadIdx.x;
    if (id >= 3136) return;
    const float* W = blockIdx.y ? w2 : w1;
    float* dst = blockIdx.y ? stab2 : stab1;
    const int oc = id / 49, p = id % 49;
    const int py = p / 7, px = p % 7;
    float s = 0.f;
    #pragma unroll
    for (int ky = 0; ky < 3; ++ky) {
        int iy = py - 1 + ky;
        if (iy < 0 || iy > 6) continue;
        #pragma unroll
        for (int kx = 0; kx < 3; ++kx) {
            int ix = px - 1 + kx;
            if (ix < 0 || ix > 6) continue;
            s += W[oc*585 + ky*3 + kx];
        }
    }
    dst[id] = s;
}

__global__ __launch_bounds__(256) void prep_c1frag_kernel(
    const float* __restrict__ w1, short* __restrict__ afc1)
{
    const int e = blockIdx.x * 256 + threadIdx.x;   // < 2048
    const int j = e & 7, lane = (e >> 3) & 63, mtq = e >> 9;
    const int m = mtq*16 + (lane & 15);
    const int k = ((lane >> 4) & 3)*8 + j;
    float v = (k < 27) ? w1[m*27 + k] : 0.f;
    afc1[e] = (short)f2bf(v);
}

__global__ __launch_bounds__(256) void prep_c23frag_kernel(
    const float* __restrict__ w2, const float* __restrict__ w3,
    short* __restrict__ afc2, short* __restrict__ afc3)
{
    const int e = blockIdx.x * 256 + threadIdx.x;   // < 65536
    const float* W = blockIdx.y ? w3 : w2;
    short* dst = blockIdx.y ? afc3 : afc2;
    const int j = e & 7, lane = (e >> 3) & 63, kt = (e >> 9) & 31, mtq = e >> 14;
    const int m = mtq*16 + (lane & 15);
    const int k = kt*32 + ((lane >> 4) & 3)*8 + j;
    const int tap = k >> 6, ic = k & 63;
    dst[e] = (short)f2bf(W[m*1024 + ic*16 + tap]);
}

// ---------------------------------------------------------------------------
// conv1 + GN1 + ReLU fused (unchanged; known good)
// ---------------------------------------------------------------------------
__global__ __launch_bounds__(512, 1) void conv1_fused(
    const float* __restrict__ x, const short* __restrict__ afc1,
    const float* __restrict__ bias,
    const float* __restrict__ g1w, const float* __restrict__ g1b,
    short* __restrict__ h1pad)
{
    __shared__ float xs[3072];
    __shared__ float gnred[128], gnq[128];
    __shared__ float s_mean[32], s_rstd[32];

    const int t = threadIdx.x, b = blockIdx.x;
    const int w = t >> 6, l = t & 63, lhi = (l >> 4) & 3, llo = l & 15;
    const int mt = w & 3, sub = w >> 2;
    const int oc0 = mt*16 + lhi*4;

    for (int i = t; i < 3072; i += 512) xs[i] = x[b*3072 + i];

    bf16x8 afr = *(const bf16x8*)(afc1 + ((size_t)(mt*64 + l))*8);

    int boff[8]; bool bval[8];
    #pragma unroll
    for (int j = 0; j < 8; ++j) {
        int k = lhi*8 + j;
        bval[j] = (k < 27);
        int kk = bval[j] ? k : 0;
        int c = kk / 9, tap = kk % 9;
        boff[j] = c*1024 + (tap/3)*32 + (tap%3);
    }
    f32x4 bia = *(const f32x4*)&bias[oc0];
    __syncthreads();

    f32x4 acc[29];
    float s[4] = {0,0,0,0}, q[4] = {0,0,0,0};
    #pragma unroll
    for (int i = 0; i < 29; ++i) {
        const int nt = sub*29 + i;
        f32x4 a = {0.f,0.f,0.f,0.f};
        if (nt < 57) {
            const int p = nt*16 + llo;
            const int pc = p < 900 ? p : 899;
            const int base = (pc/30)*32 + (pc%30);
            union { bf16x8 v; unsigned u[4]; } bb;
            #pragma unroll
            for (int jj = 0; jj < 4; ++jj) {
                float e0 = bval[2*jj]   ? xs[boff[2*jj]   + base] : 0.f;
                float e1 = bval[2*jj+1] ? xs[boff[2*jj+1] + base] : 0.f;
                bb.u[jj] = f2bf2(e0, e1);
            }
            a = MFMA16(afr, bb.v, a);
            #pragma unroll
            for (int r = 0; r < 4; ++r) {
                a[r] += bia[r];
                if (p < 900) { s[r] += a[r]; q[r] += a[r]*a[r]; }
            }
        }
        acc[i] = a;
    }

    #pragma unroll
    for (int off = 1; off < 16; off <<= 1) {
        #pragma unroll
        for (int r = 0; r < 4; ++r) {
            s[r] += __shfl_xor(s[r], off);
            q[r] += __shfl_xor(q[r], off);
        }
    }
    if (llo == 0) {
        #pragma unroll
        for (int r = 0; r < 4; ++r) {
            gnred[w*16 + lhi*4 + r] = s[r];
            gnq[w*16 + lhi*4 + r]   = q[r];
        }
    }
    __syncthreads();
    if (t < 32) {
        const int oc = t*2;
        const int mtg = oc >> 4, lh = (oc >> 2) & 3, r0 = oc & 3;
        const int i0 = mtg*16 + lh*4 + r0;
        float ss = gnred[i0] + gnred[i0+1] + gnred[i0+64] + gnred[i0+65];
        float qq = gnq[i0]   + gnq[i0+1]   + gnq[i0+64]   + gnq[i0+65];
        float m = ss * (1.f/1800.f);
        float var = qq * (1.f/1800.f) - m*m;
        s_mean[t] = m; s_rstd[t] = rsqrtf(var + 1e-5f);
    }
    __syncthreads();

    const int g0 = oc0 >> 1;
    const float m0 = s_mean[g0],   rs0 = s_rstd[g0];
    const float m1 = s_mean[g0+1], rs1 = s_rstd[g0+1];
    const float w0 = g1w[oc0], w1v = g1w[oc0+1], w2v = g1w[oc0+2], w3v = g1w[oc0+3];
    const float b0 = g1b[oc0], b1v_ = g1b[oc0+1], b2v_ = g1b[oc0+2], b3v_ = g1b[oc0+3];
    char* hb = (char*)h1pad + (size_t)b*131200;

    #pragma unroll
    for (int i = 0; i < 29; ++i) {
        const int nt = sub*29 + i;
        if (nt >= 57) continue;
        const int p = nt*16 + llo;
        if (p >= 900) continue;
        const int pidx = (p/30 + 1)*32 + (p%30 + 1);
        float v0 = fmaxf((acc[i][0]-m0)*rs0*w0  + b0,   0.f);
        float v1 = fmaxf((acc[i][1]-m0)*rs0*w1v + b1v_, 0.f);
        float v2 = fmaxf((acc[i][2]-m1)*rs1*w2v + b2v_, 0.f);
        float v3 = fmaxf((acc[i][3]-m1)*rs1*w3v + b3v_, 0.f);
        uint2 pk; pk.x = f2bf2(v0, v1); pk.y = f2bf2(v2, v3);
        *(uint2*)(hb + (oc0>>3)*16400 + pidx*16 + ((oc0&7)<<1)) = pk;
    }
    for (int u = t; u < 992; u += 512) {
        const int bp = u >> 3, c8 = u & 7;
        int pidx;
        if (bp < 32) pidx = bp;
        else if (bp < 64) pidx = 31*32 + (bp - 32);
        else if (bp < 94) pidx = (bp - 64 + 1)*32;
        else pidx = (bp - 94 + 1)*32 + 31;
        uint4 z; z.x = z.y = z.z = z.w = 0u;
        *(uint4*)(hb + c8*16400 + pidx*16) = z;
    }
}

// ---------------------------------------------------------------------------
// conv2 + GN2 + ReLU fused (unchanged)
// ---------------------------------------------------------------------------
#define CONV2_LDS 132480
__global__ __launch_bounds__(512, 1) void conv2_fused(
    const short* __restrict__ h1pad, const short* __restrict__ afc2,
    const float* __restrict__ bias,
    const float* __restrict__ g2w, const float* __restrict__ g2b,
    short* __restrict__ h2pad)
{
    extern __shared__ char smem[];
    char*  sin    = smem;
    float* gnred  = (float*)(smem + 131200);
    float* gnq    = (float*)(smem + 131712);
    float* s_mean = (float*)(smem + 132224);
    float* s_rstd = (float*)(smem + 132352);

    const int t = threadIdx.x, b = blockIdx.x;
    const int w = t >> 6, l = t & 63, lhi = (l >> 4) & 3, llo = l & 15;
    const int mt = w >> 1, half = w & 1;
    const int oc0 = mt*16 + lhi*4;

    {
        const uint4* src = (const uint4*)((const char*)h1pad + (size_t)b*131200);
        uint4* dst = (uint4*)sin;
        for (int i = t; i < 8200; i += 512) dst[i] = src[i];
    }
    bf16x8 aw[32];
    #pragma unroll
    for (int kt = 0; kt < 32; ++kt)
        aw[kt] = *(const bf16x8*)(afc2 + ((size_t)((mt*32 + kt)*64 + l))*8);
    f32x4 bia = *(const f32x4*)&bias[oc0];
    __syncthreads();

    f32x4 acc[8];
    #pragma unroll
    for (int i = 0; i < 8; ++i) acc[i] = (f32x4){0.f,0.f,0.f,0.f};

    #pragma unroll
    for (int i = 0; i < 8; ++i) {
        const int nt = half*8 + i;
        if (nt > 14) continue;
        const int n = nt*16 + llo;
        const int p = n < 225 ? n : 224;
        const int oy = p/15, ox = p%15;
        #pragma unroll
        for (int kt = 0; kt < 32; ++kt) {
            const int tap = kt >> 1;
            const int ky = tap >> 2, kx = tap & 3;
            const int pidx = (oy*2 + ky)*32 + (ox*2 + kx);
            const int c8 = (kt & 1)*4 + lhi;
            bf16x8 bb = *(const bf16x8*)(sin + c8*16400 + pidx*16);
            acc[i] = MFMA16(aw[kt], bb, acc[i]);
        }
    }

    float s[4] = {0,0,0,0}, q[4] = {0,0,0,0};
    #pragma unroll
    for (int i = 0; i < 8; ++i) {
        const int nt = half*8 + i;
        if (nt > 14) continue;
        const int n = nt*16 + llo;
        #pragma unroll
        for (int r = 0; r < 4; ++r) {
            float v = acc[i][r] + bia[r];
            acc[i][r] = v;
            if (n < 225) { s[r] += v; q[r] += v*v; }
        }
    }
    #pragma unroll
    for (int off = 1; off < 16; off <<= 1) {
        #pragma unroll
        for (int r = 0; r < 4; ++r) {
            s[r] += __shfl_xor(s[r], off);
            q[r] += __shfl_xor(q[r], off);
        }
    }
    if (llo == 0) {
        #pragma unroll
        for (int r = 0; r < 4; ++r) {
            gnred[w*16 + lhi*4 + r] = s[r];
            gnq[w*16 + lhi*4 + r]   = q[r];
        }
    }
    __syncthreads();
    if (t < 32) {
        const int oc = t*2;
        const int mtg = oc >> 4, lh = (oc >> 2) & 3, r0 = oc & 3;
        const int i0 = (mtg*2)*16 + lh*4 + r0;
        float ss = gnred[i0] + gnred[i0+1] + gnred[i0+16] + gnred[i0+17];
        float qq = gnq[i0]   + gnq[i0+1]   + gnq[i0+16]   + gnq[i0+17];
        float m = ss * (1.f/450.f);
        float var = qq * (1.f/450.f) - m*m;
        s_mean[t] = m; s_rstd[t] = rsqrtf(var + 1e-5f);
    }
    __syncthreads();

    const int g0 = oc0 >> 1;
    const float m0 = s_mean[g0],   rs0 = s_rstd[g0];
    const float m1 = s_mean[g0+1], rs1 = s_rstd[g0+1];
    const float w0 = g2w[oc0], w1v = g2w[oc0+1], w2v = g2w[oc0+2], w3v = g2w[oc0+3];
    const float b0 = g2b[oc0], b1v_ = g2b[oc0+1], b2v_ = g2b[oc0+2], b3v_ = g2b[oc0+3];
    char* hb2 = (char*)h2pad + (size_t)b*36992;

    #pragma unroll
    for (int i = 0; i < 8; ++i) {
        const int nt = half*8 + i;
        if (nt > 14) continue;
        const int n = nt*16 + llo;
        if (n >= 225) continue;
        const int pidx = (n/15 + 1)*17 + (n%15 + 1);
        float v0 = fmaxf((acc[i][0]-m0)*rs0*w0  + b0,   0.f);
        float v1 = fmaxf((acc[i][1]-m0)*rs0*w1v + b1v_, 0.f);
        float v2 = fmaxf((acc[i][2]-m1)*rs1*w2v + b2v_, 0.f);
        float v3 = fmaxf((acc[i][3]-m1)*rs1*w3v + b3v_, 0.f);
        uint2 pk; pk.x = f2bf2(v0, v1); pk.y = f2bf2(v2, v3);
        *(uint2*)(hb2 + (oc0>>3)*4624 + pidx*16 + ((oc0&7)<<1)) = pk;
    }
    if (t < 512) {
        const int bp = t >> 3, c8 = t & 7;
        int pidx;
        if (bp < 17) pidx = bp;
        else if (bp < 34) pidx = 16*17 + (bp - 17);
        else if (bp < 49) pidx = (bp - 34 + 1)*17;
        else pidx = (bp - 49 + 1)*17 + 16;
        uint4 z; z.x = z.y = z.z = z.w = 0u;
        *(uint4*)(hb2 + c8*4624 + pidx*16) = z;
    }
}

// ---------------------------------------------------------------------------
// conv3 MFMA -> y fp32 (unchanged)
// ---------------------------------------------------------------------------
__global__ __launch_bounds__(512, 1) void conv3_mfma(
    const short* __restrict__ h2pad, const short* __restrict__ afc3,
    const float* __restrict__ bias, float* __restrict__ y)
{
    __shared__ __align__(16) char sin[36992];
    const int t = threadIdx.x, b = blockIdx.x;
    const int w = t >> 6, l = t & 63, lhi = (l >> 4) & 3, llo = l & 15;
    const int mt = w >> 1, half = w & 1;
    const int oc0 = mt*16 + lhi*4;

    {
        const uint4* src = (const uint4*)((const char*)h2pad + (size_t)b*36992);
        uint4* dst = (uint4*)sin;
        for (int i = t; i < 2312; i += 512) dst[i] = src[i];
    }
    bf16x8 aw[32];
    #pragma unroll
    for (int kt = 0; kt < 32; ++kt)
        aw[kt] = *(const bf16x8*)(afc3 + ((size_t)((mt*32 + kt)*64 + l))*8);
    f32x4 bia = *(const f32x4*)&bias[oc0];
    __syncthreads();

    f32x4 acc[2];
    acc[0] = (f32x4){0.f,0.f,0.f,0.f};
    acc[1] = (f32x4){0.f,0.f,0.f,0.f};
    #pragma unroll
    for (int i = 0; i < 2; ++i) {
        const int nt = half*2 + i;
        const int n = nt*16 + llo;
        const int p = n < 49 ? n : 48;
        const int oy = p/7, ox = p%7;
        #pragma unroll
        for (int kt = 0; kt < 32; ++kt) {
            const int tap = kt >> 1;
            const int ky = tap >> 2, kx = tap & 3;
            const int pidx = (oy*2 + ky)*17 + (ox*2 + kx);
            const int c8 = (kt & 1)*4 + lhi;
            bf16x8 bb = *(const bf16x8*)(sin + c8*4624 + pidx*16);
            acc[i] = MFMA16(aw[kt], bb, acc[i]);
        }
    }
    #pragma unroll
    for (int i = 0; i < 2; ++i) {
        const int n = (half*2 + i)*16 + llo;
        if (n < 49) {
            #pragma unroll
            for (int r = 0; r < 4; ++r)
                y[(size_t)b*NELEM + (oc0 + r)*49 + n] = acc[i][r] + bia[r];
        }
    }
}

// ---------------------------------------------------------------------------
// ODE + head: EXACT round-4 structure (212 us, VGPR 128, zero spill), with
// kbuf stored in bf16 -> LDS 75520 B -> 2 blocks/CU (4 waves/SIMD).
// ---------------------------------------------------------------------------
#define SGRP 104
#define KSTRS 3328          // shorts per k-buffer ([32][104] bf16)
#define ODE_LDS 75520
__global__ __launch_bounds__(512, 4) void ode_head(
    const float* __restrict__ yin,
    const short* __restrict__ af1, const short* __restrict__ af2,
    const float* __restrict__ stab1, const float* __restrict__ stab2,
    const float* __restrict__ b1v, const float* __restrict__ b2v,
    const float* __restrict__ oaw, const float* __restrict__ oab,
    const float* __restrict__ obw, const float* __restrict__ obb,
    const float* __restrict__ ocw, const float* __restrict__ ocb,
    const float* __restrict__ g3w, const float* __restrict__ g3b,
    const float* __restrict__ linw, const float* __restrict__ linb,
    float* __restrict__ out)
{
    extern __shared__ char smem[];
    float* y_l    = (float*)smem;                  // [32][104] f32   : 13312
    short* kbuf   = (short*)(smem + 13312);        // 6x[32][104] bf16: 39936
    char*  act0   = smem + 53248;                  // [8][81][16]     : 10368
    char*  act1   = smem + 63616;                  //                 : 10368
    float* gnred  = (float*)(smem + 73984);        // 128 floats
    float* soaw   = (float*)(smem + 74496);        // 64
    float* soab   = (float*)(smem + 74752);        // 64
    float* s_mean = (float*)(smem + 75008);        // 32
    float* s_rstd = (float*)(smem + 75136);        // 32
    float* s_cm   = (float*)(smem + 75264);        // 64

    const int t = threadIdx.x, b = blockIdx.x;
    const int w = t >> 6, l = t & 63, lhi = (l >> 4) & 3, llo = l & 15;
    const int mt = w >> 1;
    const int ntA = (w & 1)*2, ntB = ntA + 1;
    const int nA = ntA*16 + llo, nB = ntB*16 + llo;
    const bool vA = nA < 49, vB = nB < 49;
    const int pxA = d_sigma[nA], pxB = d_sigma[nB];
    const int paA = (pxA/7 + 1)*9 + (pxA%7 + 1);
    const int paB = (pxB/7 + 1)*9 + (pxB%7 + 1);
    const int oc0 = mt*16 + lhi*4;
    const int g16 = t >> 4, sub = t & 15;

    // ---- init ----
    for (int u = t; u < 3136; u += 512) {
        const int g = u / 98, e = u - g*98;
        y_l[g*SGRP + e] = yin[(size_t)b*NELEM + u];
    }
    for (int i = t; i < 5184; i += 512) ((unsigned*)act0)[i] = 0u;   // act0+act1
    if (t < 64) { soaw[t] = oaw[t]; soab[t] = oab[t]; }

    float stabA1[4], stabB1[4], stabA2[4], stabB2[4];
    #pragma unroll
    for (int r = 0; r < 4; ++r) {
        stabA1[r] = stab1[(oc0 + r)*49 + pxA];
        stabB1[r] = stab1[(oc0 + r)*49 + pxB];
        stabA2[r] = stab2[(oc0 + r)*49 + pxA];
        stabB2[r] = stab2[(oc0 + r)*49 + pxB];
    }
    const f32x4 bia1 = *(const f32x4*)&b1v[oc0];
    const f32x4 bia2 = *(const f32x4*)&b2v[oc0];
    const f32x4 gwB = *(const f32x4*)&obw[oc0];
    const f32x4 gbB = *(const f32x4*)&obb[oc0];
    const f32x4 gwC = *(const f32x4*)&ocw[oc0];
    const f32x4 gbC = *(const f32x4*)&ocb[oc0];
    __syncthreads();

    const float hf  = (float)(1.0/6.0);
    const float C10 = (float)((1.0/6.0)*(1.0/5.0));
    const float C20 = (float)((1.0/6.0)*(3.0/40.0)),  C21 = (float)((1.0/6.0)*(9.0/40.0));
    const float C30 = (float)((1.0/6.0)*(44.0/45.0)), C31 = (float)((1.0/6.0)*(-56.0/15.0)), C32 = (float)((1.0/6.0)*(32.0/9.0));
    const float C40 = (float)((1.0/6.0)*(19372.0/6561.0)), C41 = (float)((1.0/6.0)*(-25360.0/2187.0)),
                C42 = (float)((1.0/6.0)*(64448.0/6561.0)), C43 = (float)((1.0/6.0)*(-212.0/729.0));
    const float C50 = (float)((1.0/6.0)*(9017.0/3168.0)), C51 = (float)((1.0/6.0)*(-355.0/33.0)),
                C52 = (float)((1.0/6.0)*(46732.0/5247.0)), C53 = (float)((1.0/6.0)*(49.0/176.0)),
                C54 = (float)((1.0/6.0)*(-5103.0/18656.0));
    const float B0 = (float)((1.0/6.0)*(35.0/384.0)), B2c = (float)((1.0/6.0)*(500.0/1113.0)),
                B3c = (float)((1.0/6.0)*(125.0/192.0)), B4c = (float)((1.0/6.0)*(-2187.0/6784.0)),
                B5c = (float)((1.0/6.0)*(11.0/84.0));

    for (int step = 0; step < 6; ++step) {
        const float t0 = (float)step * hf;
        for (int stage = 0; stage < 6; ++stage) {
            float cA=0.f, cB=0.f, cC=0.f, cD=0.f, cE=0.f, tf=0.f;
            if (stage == 1)      { cA=C10; tf = 0.2f; }
            else if (stage == 2) { cA=C20; cB=C21; tf = 0.3f; }
            else if (stage == 3) { cA=C30; cB=C31; cC=C32; tf = 0.8f; }
            else if (stage == 4) { cA=C40; cB=C41; cC=C42; cD=C43; tf = (float)(8.0/9.0); }
            else if (stage == 5) { cA=C50; cB=C51; cC=C52; cD=C53; cE=C54; tf = 1.f; }
            const float tval = t0 + hf*tf;

            // ---- phase 1: combine (fp32 y + bf16 k) + GN_oa + act0 write ----
            {
                const float* Yg = y_l + g16*SGRP;
                const short* Kg = kbuf + g16*SGRP;
                const int e0 = 4*sub;
                const int n1 = (sub < 8) ? 4 : ((sub == 8) ? 2 : 0);
                const int e1 = 64 + 4*sub;

                f32x4 va, vb = {0.f,0.f,0.f,0.f};
                {
                    f32x4 xv = *(const f32x4*)(Yg + e0);
                    if (stage > 0) xv += cA * ld_k4(Kg + 0*KSTRS + e0);
                    if (stage > 1) xv += cB * ld_k4(Kg + 1*KSTRS + e0);
                    if (stage > 2) xv += cC * ld_k4(Kg + 2*KSTRS + e0);
                    if (stage > 3) xv += cD * ld_k4(Kg + 3*KSTRS + e0);
                    if (stage > 4) xv += cE * ld_k4(Kg + 4*KSTRS + e0);
                    va = xv;
                }
                if (n1 == 4) {
                    f32x4 xv = *(const f32x4*)(Yg + e1);
                    if (stage > 0) xv += cA * ld_k4(Kg + 0*KSTRS + e1);
                    if (stage > 1) xv += cB * ld_k4(Kg + 1*KSTRS + e1);
                    if (stage > 2) xv += cC * ld_k4(Kg + 2*KSTRS + e1);
                    if (stage > 3) xv += cD * ld_k4(Kg + 3*KSTRS + e1);
                    if (stage > 4) xv += cE * ld_k4(Kg + 4*KSTRS + e1);
                    vb = xv;
                } else if (n1 == 2) {
                    float x0 = Yg[96], x1 = Yg[97];
                    if (stage > 0) { x0 = fmaf(cA, bf2f(Kg[0*KSTRS+96]), x0); x1 = fmaf(cA, bf2f(Kg[0*KSTRS+97]), x1); }
                    if (stage > 1) { x0 = fmaf(cB, bf2f(Kg[1*KSTRS+96]), x0); x1 = fmaf(cB, bf2f(Kg[1*KSTRS+97]), x1); }
                    if (stage > 2) { x0 = fmaf(cC, bf2f(Kg[2*KSTRS+96]), x0); x1 = fmaf(cC, bf2f(Kg[2*KSTRS+97]), x1); }
                    if (stage > 3) { x0 = fmaf(cD, bf2f(Kg[3*KSTRS+96]), x0); x1 = fmaf(cD, bf2f(Kg[3*KSTRS+97]), x1); }
                    if (stage > 4) { x0 = fmaf(cE, bf2f(Kg[4*KSTRS+96]), x0); x1 = fmaf(cE, bf2f(Kg[4*KSTRS+97]), x1); }
                    vb[0] = x0; vb[1] = x1;
                }

                float s = va[0]+va[1]+va[2]+va[3];
                float q = va[0]*va[0]+va[1]*va[1]+va[2]*va[2]+va[3]*va[3];
                if (n1 >= 2) { s += vb[0]+vb[1]; q += vb[0]*vb[0]+vb[1]*vb[1]; }
                if (n1 == 4) { s += vb[2]+vb[3]; q += vb[2]*vb[2]+vb[3]*vb[3]; }
                s += __shfl_xor(s, 1); q += __shfl_xor(q, 1);
                s += __shfl_xor(s, 2); q += __shfl_xor(q, 2);
                s += __shfl_xor(s, 4); q += __shfl_xor(q, 4);
                s += __shfl_xor(s, 8); q += __shfl_xor(q, 8);
                const float m = s * (1.f/98.f);
                const float rs = rsqrtf(q * (1.f/98.f) - m*m + 1e-5f);
                const float w0 = soaw[2*g16], w1s = soaw[2*g16+1];
                const float bb0 = soab[2*g16], bb1 = soab[2*g16+1];

                #pragma unroll
                for (int j2 = 0; j2 < 4; ++j2) {
                    const int e = e0 + j2;
                    const int odd = e >= 49 ? 1 : 0;
                    const int ch = 2*g16 + odd;
                    const int p = e - 49*odd;
                    float nv = fmaxf((va[j2] - m)*rs*(odd ? w1s : w0) + (odd ? bb1 : bb0), 0.f);
                    const int pa = (p/7 + 1)*9 + (p%7) + 1;
                    *(unsigned short*)(act0 + (ch>>3)*1296 + pa*16 + ((ch&7)<<1)) = f2bf(nv);
                }
                for (int j2 = 0; j2 < n1; ++j2) {
                    const int e = e1 + j2;
                    const int odd = e >= 49 ? 1 : 0;
                    const int ch = 2*g16 + odd;
                    const int p = e - 49*odd;
                    float nv = fmaxf((vb[j2] - m)*rs*(odd ? w1s : w0) + (odd ? bb1 : bb0), 0.f);
                    const int pa = (p/7 + 1)*9 + (p%7) + 1;
                    *(unsigned short*)(act0 + (ch>>3)*1296 + pa*16 + ((ch&7)<<1)) = f2bf(nv);
                }
            }
            __syncthreads();   // S1: act0 ready

            float v0[4], v1[4];
            // ---- conv1 MFMA ----
            {
                bf16x8 aw[18];
                #pragma unroll
                for (int kt = 0; kt < 18; ++kt)
                    aw[kt] = *(const bf16x8*)(af1 + ((size_t)(mt*18 + kt)*64 + l)*8);
                f32x4 acc0 = {0.f,0.f,0.f,0.f}, acc1 = {0.f,0.f,0.f,0.f};
                #pragma unroll
                for (int kt = 0; kt < 18; ++kt) {
                    const int tap = kt >> 1;
                    const int dB = ((tap/3 - 1)*9 + (tap%3 - 1))*16;
                    const int cb = ((kt & 1)*4 + lhi)*1296;
                    bf16x8 bb0 = *(const bf16x8*)(act0 + cb + paA*16 + dB);
                    bf16x8 bb1 = *(const bf16x8*)(act0 + cb + paB*16 + dB);
                    acc0 = MFMA16(aw[kt], bb0, acc0);
                    acc1 = MFMA16(aw[kt], bb1, acc1);
                }
                #pragma unroll
                for (int r = 0; r < 4; ++r) {
                    v0[r] = acc0[r] + bia1[r] + tval * stabA1[r];
                    v1[r] = acc1[r] + bia1[r] + tval * stabB1[r];
                }
            }
            // GN_ob stats
            {
                float s0=0.f,q0=0.f,s1=0.f,q1=0.f;
                if (vA) { s0 += v0[0]+v0[1]; q0 += v0[0]*v0[0]+v0[1]*v0[1];
                          s1 += v0[2]+v0[3]; q1 += v0[2]*v0[2]+v0[3]*v0[3]; }
                if (vB) { s0 += v1[0]+v1[1]; q0 += v1[0]*v1[0]+v1[1]*v1[1];
                          s1 += v1[2]+v1[3]; q1 += v1[2]*v1[2]+v1[3]*v1[3]; }
                #pragma unroll
                for (int off = 1; off < 16; off <<= 1) {
                    s0 += __shfl_xor(s0, off); q0 += __shfl_xor(q0, off);
                    s1 += __shfl_xor(s1, off); q1 += __shfl_xor(q1, off);
                }
                if (llo == 0) {
                    float* gp = gnred + w*16 + lhi*4;
                    gp[0]=s0; gp[1]=q0; gp[2]=s1; gp[3]=q1;
                }
            }
            __syncthreads();   // S2: gnred ready
            {
                const int gb = mt*32 + lhi*4;
                const float sg0 = gnred[gb]   + gnred[gb+16];
                const float qg0 = gnred[gb+1] + gnred[gb+17];
                const float sg1 = gnred[gb+2] + gnred[gb+18];
                const float qg1 = gnred[gb+3] + gnred[gb+19];
                const float m0 = sg0*(1.f/98.f);
                const float r0 = rsqrtf(qg0*(1.f/98.f) - m0*m0 + 1e-5f);
                const float m1 = sg1*(1.f/98.f);
                const float r1 = rsqrtf(qg1*(1.f/98.f) - m1*m1 + 1e-5f);
                v0[0] = fmaxf((v0[0]-m0)*r0*gwB[0]+gbB[0], 0.f);
                v0[1] = fmaxf((v0[1]-m0)*r0*gwB[1]+gbB[1], 0.f);
                v0[2] = fmaxf((v0[2]-m1)*r1*gwB[2]+gbB[2], 0.f);
                v0[3] = fmaxf((v0[3]-m1)*r1*gwB[3]+gbB[3], 0.f);
                v1[0] = fmaxf((v1[0]-m0)*r0*gwB[0]+gbB[0], 0.f);
                v1[1] = fmaxf((v1[1]-m0)*r0*gwB[1]+gbB[1], 0.f);
                v1[2] = fmaxf((v1[2]-m1)*r1*gwB[2]+gbB[2], 0.f);
                v1[3] = fmaxf((v1[3]-m1)*r1*gwB[3]+gbB[3], 0.f);
                if (vA) {
                    uint2 pk; pk.x = f2bf2(v0[0], v0[1]); pk.y = f2bf2(v0[2], v0[3]);
                    *(uint2*)(act1 + (oc0>>3)*1296 + paA*16 + ((oc0&7)<<1)) = pk;
                }
                if (vB) {
                    uint2 pk; pk.x = f2bf2(v1[0], v1[1]); pk.y = f2bf2(v1[2], v1[3]);
                    *(uint2*)(act1 + (oc0>>3)*1296 + paB*16 + ((oc0&7)<<1)) = pk;
                }
            }
            __syncthreads();   // S3: act1 ready

            // ---- conv2 MFMA ----
            {
                bf16x8 aw[18];
                #pragma unroll
                for (int kt = 0; kt < 18; ++kt)
                    aw[kt] = *(const bf16x8*)(af2 + ((size_t)(mt*18 + kt)*64 + l)*8);
                f32x4 acc0 = {0.f,0.f,0.f,0.f}, acc1 = {0.f,0.f,0.f,0.f};
                #pragma unroll
                for (int kt = 0; kt < 18; ++kt) {
                    const int tap = kt >> 1;
                    const int dB = ((tap/3 - 1)*9 + (tap%3 - 1))*16;
                    const int cb = ((kt & 1)*4 + lhi)*1296;
                    bf16x8 bb0 = *(const bf16x8*)(act1 + cb + paA*16 + dB);
                    bf16x8 bb1 = *(const bf16x8*)(act1 + cb + paB*16 + dB);
                    acc0 = MFMA16(aw[kt], bb0, acc0);
                    acc1 = MFMA16(aw[kt], bb1, acc1);
                }
                #pragma unroll
                for (int r = 0; r < 4; ++r) {
                    v0[r] = acc0[r] + bia2[r] + tval * stabA2[r];
                    v1[r] = acc1[r] + bia2[r] + tval * stabB2[r];
                }
            }
            {
                float s0=0.f,q0=0.f,s1=0.f,q1=0.f;
                if (vA) { s0 += v0[0]+v0[1]; q0 += v0[0]*v0[0]+v0[1]*v0[1];
                          s1 += v0[2]+v0[3]; q1 += v0[2]*v0[2]+v0[3]*v0[3]; }
                if (vB) { s0 += v1[0]+v1[1]; q0 += v1[0]*v1[0]+v1[1]*v1[1];
                          s1 += v1[2]+v1[3]; q1 += v1[2]*v1[2]+v1[3]*v1[3]; }
                #pragma unroll
                for (int off = 1; off < 16; off <<= 1) {
                    s0 += __shfl_xor(s0, off); q0 += __shfl_xor(q0, off);
                    s1 += __shfl_xor(s1, off); q1 += __shfl_xor(q1, off);
                }
                if (llo == 0) {
                    float* gp = gnred + w*16 + lhi*4;
                    gp[0]=s0; gp[1]=q0; gp[2]=s1; gp[3]=q1;
                }
            }
            __syncthreads();   // S4: gnred ready
            {
                const int gb = mt*32 + lhi*4;
                const float sg0 = gnred[gb]   + gnred[gb+16];
                const float qg0 = gnred[gb+1] + gnred[gb+17];
                const float sg1 = gnred[gb+2] + gnred[gb+18];
                const float qg1 = gnred[gb+3] + gnred[gb+19];
                const float m0 = sg0*(1.f/98.f);
                const float r0 = rsqrtf(qg0*(1.f/98.f) - m0*m0 + 1e-5f);
                const float m1 = sg1*(1.f/98.f);
                const float r1 = rsqrtf(qg1*(1.f/98.f) - m1*m1 + 1e-5f);
                short* kd = kbuf + stage*KSTRS;
                const int gA = oc0 >> 1;
                if (vA) {
                    kd[gA*SGRP + pxA]          = (short)cvtpk((v0[0]-m0)*r0*gwC[0]+gbC[0], 0.f);
                    kd[gA*SGRP + 49 + pxA]     = (short)cvtpk((v0[1]-m0)*r0*gwC[1]+gbC[1], 0.f);
                    kd[(gA+1)*SGRP + pxA]      = (short)cvtpk((v0[2]-m1)*r1*gwC[2]+gbC[2], 0.f);
                    kd[(gA+1)*SGRP + 49 + pxA] = (short)cvtpk((v0[3]-m1)*r1*gwC[3]+gbC[3], 0.f);
                }
                if (vB) {
                    kd[gA*SGRP + pxB]          = (short)cvtpk((v1[0]-m0)*r0*gwC[0]+gbC[0], 0.f);
                    kd[gA*SGRP + 49 + pxB]     = (short)cvtpk((v1[1]-m0)*r0*gwC[1]+gbC[1], 0.f);
                    kd[(gA+1)*SGRP + pxB]      = (short)cvtpk((v1[2]-m1)*r1*gwC[2]+gbC[2], 0.f);
                    kd[(gA+1)*SGRP + 49 + pxB] = (short)cvtpk((v1[3]-m1)*r1*gwC[3]+gbC[3], 0.f);
                }
            }
            __syncthreads();   // S5: k ready

            if (stage == 5) {
                float* Yg = y_l + g16*SGRP;
                const short* Kg = kbuf + g16*SGRP;
                const int e0 = 4*sub;
                {
                    f32x4 v = *(const f32x4*)(Yg + e0);
                    v += B0  * ld_k4(Kg + 0*KSTRS + e0);
                    v += B2c * ld_k4(Kg + 2*KSTRS + e0);
                    v += B3c * ld_k4(Kg + 3*KSTRS + e0);
                    v += B4c * ld_k4(Kg + 4*KSTRS + e0);
                    v += B5c * ld_k4(Kg + 5*KSTRS + e0);
                    *(f32x4*)(Yg + e0) = v;
                }
                if (sub < 8) {
                    const int e1 = 64 + 4*sub;
                    f32x4 v = *(const f32x4*)(Yg + e1);
                    v += B0  * ld_k4(Kg + 0*KSTRS + e1);
                    v += B2c * ld_k4(Kg + 2*KSTRS + e1);
                    v += B3c * ld_k4(Kg + 3*KSTRS + e1);
                    v += B4c * ld_k4(Kg + 4*KSTRS + e1);
                    v += B5c * ld_k4(Kg + 5*KSTRS + e1);
                    *(f32x4*)(Yg + e1) = v;
                } else if (sub == 8) {
                    #pragma unroll
                    for (int j2 = 0; j2 < 2; ++j2) {
                        const int e = 96 + j2;
                        float v = Yg[e];
                        v = fmaf(B0,  bf2f(Kg[0*KSTRS+e]), v);
                        v = fmaf(B2c, bf2f(Kg[2*KSTRS+e]), v);
                        v = fmaf(B3c, bf2f(Kg[3*KSTRS+e]), v);
                        v = fmaf(B4c, bf2f(Kg[4*KSTRS+e]), v);
                        v = fmaf(B5c, bf2f(Kg[5*KSTRS+e]), v);
                        Yg[e] = v;
                    }
                }
                __syncthreads();   // S6: y updated
            }
        }
    }

    // ---- head: GN(g3)+ReLU -> spatial mean -> linear ----
    {
        float s = 0.f, q = 0.f;
        const float* Yg = y_l + g16*SGRP;
        for (int e = sub; e < 98; e += 16) {
            float v = Yg[e];
            s += v; q += v*v;
        }
        s += __shfl_xor(s,1); q += __shfl_xor(q,1);
        s += __shfl_xor(s,2); q += __shfl_xor(q,2);
        s += __shfl_xor(s,4); q += __shfl_xor(q,4);
        s += __shfl_xor(s,8); q += __shfl_xor(q,8);
        if (sub == 0) {
            float m = s * (1.f/98.f);
            float var = q * (1.f/98.f) - m*m;
            s_mean[g16] = m; s_rstd[g16] = rsqrtf(var + 1e-5f);
        }
    }
    __syncthreads();
    if (t < 64) {
        const int ch = t, g = ch >> 1;
        const float m = s_mean[g], r = s_rstd[g];
        const float ww = g3w[ch], bb = g3b[ch];
        const float* Yc = y_l + g*SGRP + (ch & 1)*49;
        float sum = 0.f;
        for (int p = 0; p < 49; ++p) {
            float v = (Yc[p] - m)*r*ww + bb;
            sum += fmaxf(v, 0.f);
        }
        s_cm[ch] = sum * (1.f/49.f);
    }
    __syncthreads();
    if (t < 10) {
        float a = linb[t];
        for (int c = 0; c < 64; ++c) a = fmaf(s_cm[c], linw[t*64 + c], a);
        out[b*10 + t] = a;
    }
}

// ---------------------------------------------------------------------------
// Host launch
// ---------------------------------------------------------------------------
extern "C" void kernel_launch(void* const* d_in, const int* in_sizes, int n_in,
                              void* d_out, int out_size, void* d_ws, size_t ws_size,
                              hipStream_t stream)
{
    const float* x      = (const float*)d_in[0];
    const float* c1_w   = (const float*)d_in[1];
    const float* c1_b   = (const float*)d_in[2];
    const float* g1_w   = (const float*)d_in[3];
    const float* g1_b   = (const float*)d_in[4];
    const float* c2_w   = (const float*)d_in[5];
    const float* c2_b   = (const float*)d_in[6];
    const float* g2_w   = (const float*)d_in[7];
    const float* g2_b   = (const float*)d_in[8];
    const float* c3_w   = (const float*)d_in[9];
    const float* c3_b   = (const float*)d_in[10];
    const float* oa_w   = (const float*)d_in[11];
    const float* oa_b   = (const float*)d_in[12];
    const float* occ1_w = (const float*)d_in[13];
    const float* occ1_b = (const float*)d_in[14];
    const float* ob_w   = (const float*)d_in[15];
    const float* ob_b   = (const float*)d_in[16];
    const float* occ2_w = (const float*)d_in[17];
    const float* occ2_b = (const float*)d_in[18];
    const float* oc_w   = (const float*)d_in[19];
    const float* oc_b   = (const float*)d_in[20];
    const float* g3_w   = (const float*)d_in[21];
    const float* g3_b   = (const float*)d_in[22];
    const float* lin_w  = (const float*)d_in[23];
    const float* lin_b  = (const float*)d_in[24];
    float* out = (float*)d_out;

    float* ws = (float*)d_ws;
    size_t off = 0;
    float* y     = ws + off; off += 802816;
    float* stab1 = ws + off; off += 3136;
    float* stab2 = ws + off; off += 3136;
    short* af1   = (short*)(ws + off); off += 18432;    // 36864 shorts
    short* af2   = (short*)(ws + off); off += 18432;
    short* afc1  = (short*)(ws + off); off += 1024;     // 2048 shorts
    short* afc2  = (short*)(ws + off); off += 32768;    // 65536 shorts
    short* afc3  = (short*)(ws + off); off += 32768;
    short* h1pad = (short*)(ws + off); off += 8396800;  // 256*65600 shorts
    short* h2pad = (short*)(ws + off); off += 2367488;  // 256*18496 shorts

    // prep (weights constant per launch)
    prep_afrag_kernel<<<dim3(144, 2), 256, 0, stream>>>(occ1_w, occ2_w, af1, af2);
    prep_stab_kernel<<<dim3(13, 2), 256, 0, stream>>>(occ1_w, occ2_w, stab1, stab2);
    prep_c1frag_kernel<<<8, 256, 0, stream>>>(c1_w, afc1);
    prep_c23frag_kernel<<<dim3(256, 2), 256, 0, stream>>>(c2_w, c3_w, afc2, afc3);

    // preamble CNN (fused, per-image MFMA)
    conv1_fused<<<B, 512, 0, stream>>>(x, afc1, c1_b, g1_w, g1_b, h1pad);
    conv2_fused<<<B, 512, CONV2_LDS, stream>>>(h1pad, afc2, c2_b, g2_w, g2_b, h2pad);
    conv3_mfma<<<B, 512, 0, stream>>>(h2pad, afc3, c3_b, y);

    // full ODE + head, one launch (75.5 KB LDS -> 2 blocks/CU)
    ode_head<<<B, 512, ODE_LDS, stream>>>(y, af1, af2, stab1, stab2,
        occ1_b, occ2_b, oa_w, oa_b, ob_w, ob_b, oc_w, oc_b,
        g3_w, g3_b, lin_w, lin_b, out);
}

// Round 10
// 255.982 us; speedup vs baseline: 2.9377x; 2.5350x over previous
//
#include <hip/hip_runtime.h>
#include <hip/hip_bf16.h>

#define B 256
#define NELEM 3136          // 64*49 per image
#define TOTAL (B*NELEM)

typedef __attribute__((ext_vector_type(8))) short bf16x8;
typedef __attribute__((ext_vector_type(4))) float f32x4;

#define MFMA16(a,b,c) __builtin_amdgcn_mfma_f32_16x16x32_bf16((a),(b),(c),0,0,0)

__device__ __forceinline__ unsigned short f2bf(float f) {
    unsigned u = __float_as_uint(f);
    unsigned r = (u + 0x7fffu + ((u >> 16) & 1u)) >> 16;
    return (unsigned short)r;
}
__device__ __forceinline__ unsigned int f2bf2(float lo, float hi) {
    return (unsigned int)f2bf(lo) | ((unsigned int)f2bf(hi) << 16);
}
__device__ __forceinline__ unsigned int cvtpk(float lo, float hi) {
    unsigned int r;
    asm("v_cvt_pk_bf16_f32 %0, %1, %2" : "=v"(r) : "v"(lo), "v"(hi));
    return r;
}
__device__ __forceinline__ float bf2f(unsigned short h) {
    return __uint_as_float(((unsigned)h) << 16);
}
// 4 packed bf16 (8B aligned) -> f32x4
__device__ __forceinline__ f32x4 ld_k4(const short* p) {
    uint2 u = *(const uint2*)p;
    f32x4 r;
    r[0] = __uint_as_float(u.x << 16);
    r[1] = __uint_as_float(u.x & 0xffff0000u);
    r[2] = __uint_as_float(u.y << 16);
    r[3] = __uint_as_float(u.y & 0xffff0000u);
    return r;
}

// lane-tile -> pixel permutation: each 16-lane tile has exactly 2 pixels of
// each (pa mod 8) residue class -> conflict-free conv ds_read_b128.
__device__ const int d_sigma[64] = {
    6,12,13,19,0,20,1,7,2,8,3,9,4,10,5,11,
    18,24,25,31,26,32,27,33,14,34,15,21,16,22,17,23,
    30,36,37,43,38,44,39,45,40,46,41,47,28,48,29,35,
    42,42,42,42,42,42,42,42,42,42,42,42,42,42,42,42
};

// ---------------------------------------------------------------------------
// Weight-fragment prep kernels (unchanged, validated)
// ---------------------------------------------------------------------------
__global__ __launch_bounds__(256) void prep_afrag_kernel(
    const float* __restrict__ w1, const float* __restrict__ w2,
    short* __restrict__ af1, short* __restrict__ af2)
{
    const int e = blockIdx.x * 256 + threadIdx.x;   // < 36864
    const float* W = blockIdx.y ? w2 : w1;
    short* dst = blockIdx.y ? af2 : af1;
    const int j = e & 7;
    const int lane = (e >> 3) & 63;
    const int kt = (e >> 9) % 18;
    const int mt = (e >> 9) / 18;
    const int m = mt*16 + (lane & 15);
    const int k = kt*32 + ((lane >> 4) & 3)*8 + j;
    const int tap = k >> 6;
    const int ic  = k & 63;
    dst[e] = (short)f2bf(W[m*585 + (ic + 1)*9 + tap]);
}

__global__ __launch_bounds__(256) void prep_stab_kernel(
    const float* __restrict__ w1, const float* __restrict__ w2,
    float* __restrict__ stab1, float* __restrict__ stab2)
{
    const int id = blockIdx.x * 256 + threadIdx.x;
    if (id >= 3136) return;
    const float* W = blockIdx.y ? w2 : w1;
    float* dst = blockIdx.y ? stab2 : stab1;
    const int oc = id / 49, p = id % 49;
    const int py = p / 7, px = p % 7;
    float s = 0.f;
    #pragma unroll
    for (int ky = 0; ky < 3; ++ky) {
        int iy = py - 1 + ky;
        if (iy < 0 || iy > 6) continue;
        #pragma unroll
        for (int kx = 0; kx < 3; ++kx) {
            int ix = px - 1 + kx;
            if (ix < 0 || ix > 6) continue;
            s += W[oc*585 + ky*3 + kx];
        }
    }
    dst[id] = s;
}

__global__ __launch_bounds__(256) void prep_c1frag_kernel(
    const float* __restrict__ w1, short* __restrict__ afc1)
{
    const int e = blockIdx.x * 256 + threadIdx.x;   // < 2048
    const int j = e & 7, lane = (e >> 3) & 63, mtq = e >> 9;
    const int m = mtq*16 + (lane & 15);
    const int k = ((lane >> 4) & 3)*8 + j;
    float v = (k < 27) ? w1[m*27 + k] : 0.f;
    afc1[e] = (short)f2bf(v);
}

__global__ __launch_bounds__(256) void prep_c23frag_kernel(
    const float* __restrict__ w2, const float* __restrict__ w3,
    short* __restrict__ afc2, short* __restrict__ afc3)
{
    const int e = blockIdx.x * 256 + threadIdx.x;   // < 65536
    const float* W = blockIdx.y ? w3 : w2;
    short* dst = blockIdx.y ? afc3 : afc2;
    const int j = e & 7, lane = (e >> 3) & 63, kt = (e >> 9) & 31, mtq = e >> 14;
    const int m = mtq*16 + (lane & 15);
    const int k = kt*32 + ((lane >> 4) & 3)*8 + j;
    const int tap = k >> 6, ic = k & 63;
    dst[e] = (short)f2bf(W[m*1024 + ic*16 + tap]);
}

// ---------------------------------------------------------------------------
// conv1 + GN1 + ReLU fused (unchanged; known good)
// ---------------------------------------------------------------------------
__global__ __launch_bounds__(512, 1) void conv1_fused(
    const float* __restrict__ x, const short* __restrict__ afc1,
    const float* __restrict__ bias,
    const float* __restrict__ g1w, const float* __restrict__ g1b,
    short* __restrict__ h1pad)
{
    __shared__ float xs[3072];
    __shared__ float gnred[128], gnq[128];
    __shared__ float s_mean[32], s_rstd[32];

    const int t = threadIdx.x, b = blockIdx.x;
    const int w = t >> 6, l = t & 63, lhi = (l >> 4) & 3, llo = l & 15;
    const int mt = w & 3, sub = w >> 2;
    const int oc0 = mt*16 + lhi*4;

    for (int i = t; i < 3072; i += 512) xs[i] = x[b*3072 + i];

    bf16x8 afr = *(const bf16x8*)(afc1 + ((size_t)(mt*64 + l))*8);

    int boff[8]; bool bval[8];
    #pragma unroll
    for (int j = 0; j < 8; ++j) {
        int k = lhi*8 + j;
        bval[j] = (k < 27);
        int kk = bval[j] ? k : 0;
        int c = kk / 9, tap = kk % 9;
        boff[j] = c*1024 + (tap/3)*32 + (tap%3);
    }
    f32x4 bia = *(const f32x4*)&bias[oc0];
    __syncthreads();

    f32x4 acc[29];
    float s[4] = {0,0,0,0}, q[4] = {0,0,0,0};
    #pragma unroll
    for (int i = 0; i < 29; ++i) {
        const int nt = sub*29 + i;
        f32x4 a = {0.f,0.f,0.f,0.f};
        if (nt < 57) {
            const int p = nt*16 + llo;
            const int pc = p < 900 ? p : 899;
            const int base = (pc/30)*32 + (pc%30);
            union { bf16x8 v; unsigned u[4]; } bb;
            #pragma unroll
            for (int jj = 0; jj < 4; ++jj) {
                float e0 = bval[2*jj]   ? xs[boff[2*jj]   + base] : 0.f;
                float e1 = bval[2*jj+1] ? xs[boff[2*jj+1] + base] : 0.f;
                bb.u[jj] = f2bf2(e0, e1);
            }
            a = MFMA16(afr, bb.v, a);
            #pragma unroll
            for (int r = 0; r < 4; ++r) {
                a[r] += bia[r];
                if (p < 900) { s[r] += a[r]; q[r] += a[r]*a[r]; }
            }
        }
        acc[i] = a;
    }

    #pragma unroll
    for (int off = 1; off < 16; off <<= 1) {
        #pragma unroll
        for (int r = 0; r < 4; ++r) {
            s[r] += __shfl_xor(s[r], off);
            q[r] += __shfl_xor(q[r], off);
        }
    }
    if (llo == 0) {
        #pragma unroll
        for (int r = 0; r < 4; ++r) {
            gnred[w*16 + lhi*4 + r] = s[r];
            gnq[w*16 + lhi*4 + r]   = q[r];
        }
    }
    __syncthreads();
    if (t < 32) {
        const int oc = t*2;
        const int mtg = oc >> 4, lh = (oc >> 2) & 3, r0 = oc & 3;
        const int i0 = mtg*16 + lh*4 + r0;
        float ss = gnred[i0] + gnred[i0+1] + gnred[i0+64] + gnred[i0+65];
        float qq = gnq[i0]   + gnq[i0+1]   + gnq[i0+64]   + gnq[i0+65];
        float m = ss * (1.f/1800.f);
        float var = qq * (1.f/1800.f) - m*m;
        s_mean[t] = m; s_rstd[t] = rsqrtf(var + 1e-5f);
    }
    __syncthreads();

    const int g0 = oc0 >> 1;
    const float m0 = s_mean[g0],   rs0 = s_rstd[g0];
    const float m1 = s_mean[g0+1], rs1 = s_rstd[g0+1];
    const float w0 = g1w[oc0], w1v = g1w[oc0+1], w2v = g1w[oc0+2], w3v = g1w[oc0+3];
    const float b0 = g1b[oc0], b1v_ = g1b[oc0+1], b2v_ = g1b[oc0+2], b3v_ = g1b[oc0+3];
    char* hb = (char*)h1pad + (size_t)b*131200;

    #pragma unroll
    for (int i = 0; i < 29; ++i) {
        const int nt = sub*29 + i;
        if (nt >= 57) continue;
        const int p = nt*16 + llo;
        if (p >= 900) continue;
        const int pidx = (p/30 + 1)*32 + (p%30 + 1);
        float v0 = fmaxf((acc[i][0]-m0)*rs0*w0  + b0,   0.f);
        float v1 = fmaxf((acc[i][1]-m0)*rs0*w1v + b1v_, 0.f);
        float v2 = fmaxf((acc[i][2]-m1)*rs1*w2v + b2v_, 0.f);
        float v3 = fmaxf((acc[i][3]-m1)*rs1*w3v + b3v_, 0.f);
        uint2 pk; pk.x = f2bf2(v0, v1); pk.y = f2bf2(v2, v3);
        *(uint2*)(hb + (oc0>>3)*16400 + pidx*16 + ((oc0&7)<<1)) = pk;
    }
    for (int u = t; u < 992; u += 512) {
        const int bp = u >> 3, c8 = u & 7;
        int pidx;
        if (bp < 32) pidx = bp;
        else if (bp < 64) pidx = 31*32 + (bp - 32);
        else if (bp < 94) pidx = (bp - 64 + 1)*32;
        else pidx = (bp - 94 + 1)*32 + 31;
        uint4 z; z.x = z.y = z.z = z.w = 0u;
        *(uint4*)(hb + c8*16400 + pidx*16) = z;
    }
}

// ---------------------------------------------------------------------------
// conv2 + GN2 + ReLU fused (unchanged)
// ---------------------------------------------------------------------------
#define CONV2_LDS 132480
__global__ __launch_bounds__(512, 1) void conv2_fused(
    const short* __restrict__ h1pad, const short* __restrict__ afc2,
    const float* __restrict__ bias,
    const float* __restrict__ g2w, const float* __restrict__ g2b,
    short* __restrict__ h2pad)
{
    extern __shared__ char smem[];
    char*  sin    = smem;
    float* gnred  = (float*)(smem + 131200);
    float* gnq    = (float*)(smem + 131712);
    float* s_mean = (float*)(smem + 132224);
    float* s_rstd = (float*)(smem + 132352);

    const int t = threadIdx.x, b = blockIdx.x;
    const int w = t >> 6, l = t & 63, lhi = (l >> 4) & 3, llo = l & 15;
    const int mt = w >> 1, half = w & 1;
    const int oc0 = mt*16 + lhi*4;

    {
        const uint4* src = (const uint4*)((const char*)h1pad + (size_t)b*131200);
        uint4* dst = (uint4*)sin;
        for (int i = t; i < 8200; i += 512) dst[i] = src[i];
    }
    bf16x8 aw[32];
    #pragma unroll
    for (int kt = 0; kt < 32; ++kt)
        aw[kt] = *(const bf16x8*)(afc2 + ((size_t)((mt*32 + kt)*64 + l))*8);
    f32x4 bia = *(const f32x4*)&bias[oc0];
    __syncthreads();

    f32x4 acc[8];
    #pragma unroll
    for (int i = 0; i < 8; ++i) acc[i] = (f32x4){0.f,0.f,0.f,0.f};

    #pragma unroll
    for (int i = 0; i < 8; ++i) {
        const int nt = half*8 + i;
        if (nt > 14) continue;
        const int n = nt*16 + llo;
        const int p = n < 225 ? n : 224;
        const int oy = p/15, ox = p%15;
        #pragma unroll
        for (int kt = 0; kt < 32; ++kt) {
            const int tap = kt >> 1;
            const int ky = tap >> 2, kx = tap & 3;
            const int pidx = (oy*2 + ky)*32 + (ox*2 + kx);
            const int c8 = (kt & 1)*4 + lhi;
            bf16x8 bb = *(const bf16x8*)(sin + c8*16400 + pidx*16);
            acc[i] = MFMA16(aw[kt], bb, acc[i]);
        }
    }

    float s[4] = {0,0,0,0}, q[4] = {0,0,0,0};
    #pragma unroll
    for (int i = 0; i < 8; ++i) {
        const int nt = half*8 + i;
        if (nt > 14) continue;
        const int n = nt*16 + llo;
        #pragma unroll
        for (int r = 0; r < 4; ++r) {
            float v = acc[i][r] + bia[r];
            acc[i][r] = v;
            if (n < 225) { s[r] += v; q[r] += v*v; }
        }
    }
    #pragma unroll
    for (int off = 1; off < 16; off <<= 1) {
        #pragma unroll
        for (int r = 0; r < 4; ++r) {
            s[r] += __shfl_xor(s[r], off);
            q[r] += __shfl_xor(q[r], off);
        }
    }
    if (llo == 0) {
        #pragma unroll
        for (int r = 0; r < 4; ++r) {
            gnred[w*16 + lhi*4 + r] = s[r];
            gnq[w*16 + lhi*4 + r]   = q[r];
        }
    }
    __syncthreads();
    if (t < 32) {
        const int oc = t*2;
        const int mtg = oc >> 4, lh = (oc >> 2) & 3, r0 = oc & 3;
        const int i0 = (mtg*2)*16 + lh*4 + r0;
        float ss = gnred[i0] + gnred[i0+1] + gnred[i0+16] + gnred[i0+17];
        float qq = gnq[i0]   + gnq[i0+1]   + gnq[i0+16]   + gnq[i0+17];
        float m = ss * (1.f/450.f);
        float var = qq * (1.f/450.f) - m*m;
        s_mean[t] = m; s_rstd[t] = rsqrtf(var + 1e-5f);
    }
    __syncthreads();

    const int g0 = oc0 >> 1;
    const float m0 = s_mean[g0],   rs0 = s_rstd[g0];
    const float m1 = s_mean[g0+1], rs1 = s_rstd[g0+1];
    const float w0 = g2w[oc0], w1v = g2w[oc0+1], w2v = g2w[oc0+2], w3v = g2w[oc0+3];
    const float b0 = g2b[oc0], b1v_ = g2b[oc0+1], b2v_ = g2b[oc0+2], b3v_ = g2b[oc0+3];
    char* hb2 = (char*)h2pad + (size_t)b*36992;

    #pragma unroll
    for (int i = 0; i < 8; ++i) {
        const int nt = half*8 + i;
        if (nt > 14) continue;
        const int n = nt*16 + llo;
        if (n >= 225) continue;
        const int pidx = (n/15 + 1)*17 + (n%15 + 1);
        float v0 = fmaxf((acc[i][0]-m0)*rs0*w0  + b0,   0.f);
        float v1 = fmaxf((acc[i][1]-m0)*rs0*w1v + b1v_, 0.f);
        float v2 = fmaxf((acc[i][2]-m1)*rs1*w2v + b2v_, 0.f);
        float v3 = fmaxf((acc[i][3]-m1)*rs1*w3v + b3v_, 0.f);
        uint2 pk; pk.x = f2bf2(v0, v1); pk.y = f2bf2(v2, v3);
        *(uint2*)(hb2 + (oc0>>3)*4624 + pidx*16 + ((oc0&7)<<1)) = pk;
    }
    if (t < 512) {
        const int bp = t >> 3, c8 = t & 7;
        int pidx;
        if (bp < 17) pidx = bp;
        else if (bp < 34) pidx = 16*17 + (bp - 17);
        else if (bp < 49) pidx = (bp - 34 + 1)*17;
        else pidx = (bp - 49 + 1)*17 + 16;
        uint4 z; z.x = z.y = z.z = z.w = 0u;
        *(uint4*)(hb2 + c8*4624 + pidx*16) = z;
    }
}

// ---------------------------------------------------------------------------
// conv3 MFMA -> y fp32 (unchanged)
// ---------------------------------------------------------------------------
__global__ __launch_bounds__(512, 1) void conv3_mfma(
    const short* __restrict__ h2pad, const short* __restrict__ afc3,
    const float* __restrict__ bias, float* __restrict__ y)
{
    __shared__ __align__(16) char sin[36992];
    const int t = threadIdx.x, b = blockIdx.x;
    const int w = t >> 6, l = t & 63, lhi = (l >> 4) & 3, llo = l & 15;
    const int mt = w >> 1, half = w & 1;
    const int oc0 = mt*16 + lhi*4;

    {
        const uint4* src = (const uint4*)((const char*)h2pad + (size_t)b*36992);
        uint4* dst = (uint4*)sin;
        for (int i = t; i < 2312; i += 512) dst[i] = src[i];
    }
    bf16x8 aw[32];
    #pragma unroll
    for (int kt = 0; kt < 32; ++kt)
        aw[kt] = *(const bf16x8*)(afc3 + ((size_t)((mt*32 + kt)*64 + l))*8);
    f32x4 bia = *(const f32x4*)&bias[oc0];
    __syncthreads();

    f32x4 acc[2];
    acc[0] = (f32x4){0.f,0.f,0.f,0.f};
    acc[1] = (f32x4){0.f,0.f,0.f,0.f};
    #pragma unroll
    for (int i = 0; i < 2; ++i) {
        const int nt = half*2 + i;
        const int n = nt*16 + llo;
        const int p = n < 49 ? n : 48;
        const int oy = p/7, ox = p%7;
        #pragma unroll
        for (int kt = 0; kt < 32; ++kt) {
            const int tap = kt >> 1;
            const int ky = tap >> 2, kx = tap & 3;
            const int pidx = (oy*2 + ky)*17 + (ox*2 + kx);
            const int c8 = (kt & 1)*4 + lhi;
            bf16x8 bb = *(const bf16x8*)(sin + c8*4624 + pidx*16);
            acc[i] = MFMA16(aw[kt], bb, acc[i]);
        }
    }
    #pragma unroll
    for (int i = 0; i < 2; ++i) {
        const int n = (half*2 + i)*16 + llo;
        if (n < 49) {
            #pragma unroll
            for (int r = 0; r < 4; ++r)
                y[(size_t)b*NELEM + (oc0 + r)*49 + n] = acc[i][r] + bia[r];
        }
    }
}

// ---------------------------------------------------------------------------
// ODE + head: round-4 structure with bf16 kbuf (LDS 75520 B -> 2 blocks/CU).
// launch_bounds (512,2): the bound that reproducibly yields <=128 VGPR, no
// spill (r6/r7/r8). HW occupancy then = 2 blocks/CU from actual resources.
// ---------------------------------------------------------------------------
#define SGRP 104
#define KSTRS 3328          // shorts per k-buffer ([32][104] bf16)
#define ODE_LDS 75520
__global__ __launch_bounds__(512, 2) void ode_head(
    const float* __restrict__ yin,
    const short* __restrict__ af1, const short* __restrict__ af2,
    const float* __restrict__ stab1, const float* __restrict__ stab2,
    const float* __restrict__ b1v, const float* __restrict__ b2v,
    const float* __restrict__ oaw, const float* __restrict__ oab,
    const float* __restrict__ obw, const float* __restrict__ obb,
    const float* __restrict__ ocw, const float* __restrict__ ocb,
    const float* __restrict__ g3w, const float* __restrict__ g3b,
    const float* __restrict__ linw, const float* __restrict__ linb,
    float* __restrict__ out)
{
    extern __shared__ char smem[];
    float* y_l    = (float*)smem;                  // [32][104] f32   : 13312
    short* kbuf   = (short*)(smem + 13312);        // 6x[32][104] bf16: 39936
    char*  act0   = smem + 53248;                  // [8][81][16]     : 10368
    char*  act1   = smem + 63616;                  //                 : 10368
    float* gnred  = (float*)(smem + 73984);        // 128 floats
    float* soaw   = (float*)(smem + 74496);        // 64
    float* soab   = (float*)(smem + 74752);        // 64
    float* s_mean = (float*)(smem + 75008);        // 32
    float* s_rstd = (float*)(smem + 75136);        // 32
    float* s_cm   = (float*)(smem + 75264);        // 64

    const int t = threadIdx.x, b = blockIdx.x;
    const int w = t >> 6, l = t & 63, lhi = (l >> 4) & 3, llo = l & 15;
    const int mt = w >> 1;
    const int ntA = (w & 1)*2, ntB = ntA + 1;
    const int nA = ntA*16 + llo, nB = ntB*16 + llo;
    const bool vA = nA < 49, vB = nB < 49;
    const int pxA = d_sigma[nA], pxB = d_sigma[nB];
    const int paA = (pxA/7 + 1)*9 + (pxA%7 + 1);
    const int paB = (pxB/7 + 1)*9 + (pxB%7 + 1);
    const int oc0 = mt*16 + lhi*4;
    const int g16 = t >> 4, sub = t & 15;

    // ---- init ----
    for (int u = t; u < 3136; u += 512) {
        const int g = u / 98, e = u - g*98;
        y_l[g*SGRP + e] = yin[(size_t)b*NELEM + u];
    }
    for (int i = t; i < 5184; i += 512) ((unsigned*)act0)[i] = 0u;   // act0+act1
    if (t < 64) { soaw[t] = oaw[t]; soab[t] = oab[t]; }

    float stabA1[4], stabB1[4], stabA2[4], stabB2[4];
    #pragma unroll
    for (int r = 0; r < 4; ++r) {
        stabA1[r] = stab1[(oc0 + r)*49 + pxA];
        stabB1[r] = stab1[(oc0 + r)*49 + pxB];
        stabA2[r] = stab2[(oc0 + r)*49 + pxA];
        stabB2[r] = stab2[(oc0 + r)*49 + pxB];
    }
    const f32x4 bia1 = *(const f32x4*)&b1v[oc0];
    const f32x4 bia2 = *(const f32x4*)&b2v[oc0];
    const f32x4 gwB = *(const f32x4*)&obw[oc0];
    const f32x4 gbB = *(const f32x4*)&obb[oc0];
    const f32x4 gwC = *(const f32x4*)&ocw[oc0];
    const f32x4 gbC = *(const f32x4*)&ocb[oc0];
    __syncthreads();

    const float hf  = (float)(1.0/6.0);
    const float C10 = (float)((1.0/6.0)*(1.0/5.0));
    const float C20 = (float)((1.0/6.0)*(3.0/40.0)),  C21 = (float)((1.0/6.0)*(9.0/40.0));
    const float C30 = (float)((1.0/6.0)*(44.0/45.0)), C31 = (float)((1.0/6.0)*(-56.0/15.0)), C32 = (float)((1.0/6.0)*(32.0/9.0));
    const float C40 = (float)((1.0/6.0)*(19372.0/6561.0)), C41 = (float)((1.0/6.0)*(-25360.0/2187.0)),
                C42 = (float)((1.0/6.0)*(64448.0/6561.0)), C43 = (float)((1.0/6.0)*(-212.0/729.0));
    const float C50 = (float)((1.0/6.0)*(9017.0/3168.0)), C51 = (float)((1.0/6.0)*(-355.0/33.0)),
                C52 = (float)((1.0/6.0)*(46732.0/5247.0)), C53 = (float)((1.0/6.0)*(49.0/176.0)),
                C54 = (float)((1.0/6.0)*(-5103.0/18656.0));
    const float B0 = (float)((1.0/6.0)*(35.0/384.0)), B2c = (float)((1.0/6.0)*(500.0/1113.0)),
                B3c = (float)((1.0/6.0)*(125.0/192.0)), B4c = (float)((1.0/6.0)*(-2187.0/6784.0)),
                B5c = (float)((1.0/6.0)*(11.0/84.0));

    for (int step = 0; step < 6; ++step) {
        const float t0 = (float)step * hf;
        for (int stage = 0; stage < 6; ++stage) {
            float cA=0.f, cB=0.f, cC=0.f, cD=0.f, cE=0.f, tf=0.f;
            if (stage == 1)      { cA=C10; tf = 0.2f; }
            else if (stage == 2) { cA=C20; cB=C21; tf = 0.3f; }
            else if (stage == 3) { cA=C30; cB=C31; cC=C32; tf = 0.8f; }
            else if (stage == 4) { cA=C40; cB=C41; cC=C42; cD=C43; tf = (float)(8.0/9.0); }
            else if (stage == 5) { cA=C50; cB=C51; cC=C52; cD=C53; cE=C54; tf = 1.f; }
            const float tval = t0 + hf*tf;

            // ---- phase 1: combine (fp32 y + bf16 k) + GN_oa + act0 write ----
            {
                const float* Yg = y_l + g16*SGRP;
                const short* Kg = kbuf + g16*SGRP;
                const int e0 = 4*sub;
                const int n1 = (sub < 8) ? 4 : ((sub == 8) ? 2 : 0);
                const int e1 = 64 + 4*sub;

                f32x4 va, vb = {0.f,0.f,0.f,0.f};
                {
                    f32x4 xv = *(const f32x4*)(Yg + e0);
                    if (stage > 0) xv += cA * ld_k4(Kg + 0*KSTRS + e0);
                    if (stage > 1) xv += cB * ld_k4(Kg + 1*KSTRS + e0);
                    if (stage > 2) xv += cC * ld_k4(Kg + 2*KSTRS + e0);
                    if (stage > 3) xv += cD * ld_k4(Kg + 3*KSTRS + e0);
                    if (stage > 4) xv += cE * ld_k4(Kg + 4*KSTRS + e0);
                    va = xv;
                }
                if (n1 == 4) {
                    f32x4 xv = *(const f32x4*)(Yg + e1);
                    if (stage > 0) xv += cA * ld_k4(Kg + 0*KSTRS + e1);
                    if (stage > 1) xv += cB * ld_k4(Kg + 1*KSTRS + e1);
                    if (stage > 2) xv += cC * ld_k4(Kg + 2*KSTRS + e1);
                    if (stage > 3) xv += cD * ld_k4(Kg + 3*KSTRS + e1);
                    if (stage > 4) xv += cE * ld_k4(Kg + 4*KSTRS + e1);
                    vb = xv;
                } else if (n1 == 2) {
                    float x0 = Yg[96], x1 = Yg[97];
                    if (stage > 0) { x0 = fmaf(cA, bf2f(Kg[0*KSTRS+96]), x0); x1 = fmaf(cA, bf2f(Kg[0*KSTRS+97]), x1); }
                    if (stage > 1) { x0 = fmaf(cB, bf2f(Kg[1*KSTRS+96]), x0); x1 = fmaf(cB, bf2f(Kg[1*KSTRS+97]), x1); }
                    if (stage > 2) { x0 = fmaf(cC, bf2f(Kg[2*KSTRS+96]), x0); x1 = fmaf(cC, bf2f(Kg[2*KSTRS+97]), x1); }
                    if (stage > 3) { x0 = fmaf(cD, bf2f(Kg[3*KSTRS+96]), x0); x1 = fmaf(cD, bf2f(Kg[3*KSTRS+97]), x1); }
                    if (stage > 4) { x0 = fmaf(cE, bf2f(Kg[4*KSTRS+96]), x0); x1 = fmaf(cE, bf2f(Kg[4*KSTRS+97]), x1); }
                    vb[0] = x0; vb[1] = x1;
                }

                float s = va[0]+va[1]+va[2]+va[3];
                float q = va[0]*va[0]+va[1]*va[1]+va[2]*va[2]+va[3]*va[3];
                if (n1 >= 2) { s += vb[0]+vb[1]; q += vb[0]*vb[0]+vb[1]*vb[1]; }
                if (n1 == 4) { s += vb[2]+vb[3]; q += vb[2]*vb[2]+vb[3]*vb[3]; }
                s += __shfl_xor(s, 1); q += __shfl_xor(q, 1);
                s += __shfl_xor(s, 2); q += __shfl_xor(q, 2);
                s += __shfl_xor(s, 4); q += __shfl_xor(q, 4);
                s += __shfl_xor(s, 8); q += __shfl_xor(q, 8);
                const float m = s * (1.f/98.f);
                const float rs = rsqrtf(q * (1.f/98.f) - m*m + 1e-5f);
                const float w0 = soaw[2*g16], w1s = soaw[2*g16+1];
                const float bb0 = soab[2*g16], bb1 = soab[2*g16+1];

                #pragma unroll
                for (int j2 = 0; j2 < 4; ++j2) {
                    const int e = e0 + j2;
                    const int odd = e >= 49 ? 1 : 0;
                    const int ch = 2*g16 + odd;
                    const int p = e - 49*odd;
                    float nv = fmaxf((va[j2] - m)*rs*(odd ? w1s : w0) + (odd ? bb1 : bb0), 0.f);
                    const int pa = (p/7 + 1)*9 + (p%7) + 1;
                    *(unsigned short*)(act0 + (ch>>3)*1296 + pa*16 + ((ch&7)<<1)) = f2bf(nv);
                }
                for (int j2 = 0; j2 < n1; ++j2) {
                    const int e = e1 + j2;
                    const int odd = e >= 49 ? 1 : 0;
                    const int ch = 2*g16 + odd;
                    const int p = e - 49*odd;
                    float nv = fmaxf((vb[j2] - m)*rs*(odd ? w1s : w0) + (odd ? bb1 : bb0), 0.f);
                    const int pa = (p/7 + 1)*9 + (p%7) + 1;
                    *(unsigned short*)(act0 + (ch>>3)*1296 + pa*16 + ((ch&7)<<1)) = f2bf(nv);
                }
            }
            __syncthreads();   // S1: act0 ready

            float v0[4], v1[4];
            // ---- conv1 MFMA ----
            {
                bf16x8 aw[18];
                #pragma unroll
                for (int kt = 0; kt < 18; ++kt)
                    aw[kt] = *(const bf16x8*)(af1 + ((size_t)(mt*18 + kt)*64 + l)*8);
                f32x4 acc0 = {0.f,0.f,0.f,0.f}, acc1 = {0.f,0.f,0.f,0.f};
                #pragma unroll
                for (int kt = 0; kt < 18; ++kt) {
                    const int tap = kt >> 1;
                    const int dB = ((tap/3 - 1)*9 + (tap%3 - 1))*16;
                    const int cb = ((kt & 1)*4 + lhi)*1296;
                    bf16x8 bb0 = *(const bf16x8*)(act0 + cb + paA*16 + dB);
                    bf16x8 bb1 = *(const bf16x8*)(act0 + cb + paB*16 + dB);
                    acc0 = MFMA16(aw[kt], bb0, acc0);
                    acc1 = MFMA16(aw[kt], bb1, acc1);
                }
                #pragma unroll
                for (int r = 0; r < 4; ++r) {
                    v0[r] = acc0[r] + bia1[r] + tval * stabA1[r];
                    v1[r] = acc1[r] + bia1[r] + tval * stabB1[r];
                }
            }
            // GN_ob stats
            {
                float s0=0.f,q0=0.f,s1=0.f,q1=0.f;
                if (vA) { s0 += v0[0]+v0[1]; q0 += v0[0]*v0[0]+v0[1]*v0[1];
                          s1 += v0[2]+v0[3]; q1 += v0[2]*v0[2]+v0[3]*v0[3]; }
                if (vB) { s0 += v1[0]+v1[1]; q0 += v1[0]*v1[0]+v1[1]*v1[1];
                          s1 += v1[2]+v1[3]; q1 += v1[2]*v1[2]+v1[3]*v1[3]; }
                #pragma unroll
                for (int off = 1; off < 16; off <<= 1) {
                    s0 += __shfl_xor(s0, off); q0 += __shfl_xor(q0, off);
                    s1 += __shfl_xor(s1, off); q1 += __shfl_xor(q1, off);
                }
                if (llo == 0) {
                    float* gp = gnred + w*16 + lhi*4;
                    gp[0]=s0; gp[1]=q0; gp[2]=s1; gp[3]=q1;
                }
            }
            __syncthreads();   // S2: gnred ready
            {
                const int gb = mt*32 + lhi*4;
                const float sg0 = gnred[gb]   + gnred[gb+16];
                const float qg0 = gnred[gb+1] + gnred[gb+17];
                const float sg1 = gnred[gb+2] + gnred[gb+18];
                const float qg1 = gnred[gb+3] + gnred[gb+19];
                const float m0 = sg0*(1.f/98.f);
                const float r0 = rsqrtf(qg0*(1.f/98.f) - m0*m0 + 1e-5f);
                const float m1 = sg1*(1.f/98.f);
                const float r1 = rsqrtf(qg1*(1.f/98.f) - m1*m1 + 1e-5f);
                v0[0] = fmaxf((v0[0]-m0)*r0*gwB[0]+gbB[0], 0.f);
                v0[1] = fmaxf((v0[1]-m0)*r0*gwB[1]+gbB[1], 0.f);
                v0[2] = fmaxf((v0[2]-m1)*r1*gwB[2]+gbB[2], 0.f);
                v0[3] = fmaxf((v0[3]-m1)*r1*gwB[3]+gbB[3], 0.f);
                v1[0] = fmaxf((v1[0]-m0)*r0*gwB[0]+gbB[0], 0.f);
                v1[1] = fmaxf((v1[1]-m0)*r0*gwB[1]+gbB[1], 0.f);
                v1[2] = fmaxf((v1[2]-m1)*r1*gwB[2]+gbB[2], 0.f);
                v1[3] = fmaxf((v1[3]-m1)*r1*gwB[3]+gbB[3], 0.f);
                if (vA) {
                    uint2 pk; pk.x = f2bf2(v0[0], v0[1]); pk.y = f2bf2(v0[2], v0[3]);
                    *(uint2*)(act1 + (oc0>>3)*1296 + paA*16 + ((oc0&7)<<1)) = pk;
                }
                if (vB) {
                    uint2 pk; pk.x = f2bf2(v1[0], v1[1]); pk.y = f2bf2(v1[2], v1[3]);
                    *(uint2*)(act1 + (oc0>>3)*1296 + paB*16 + ((oc0&7)<<1)) = pk;
                }
            }
            __syncthreads();   // S3: act1 ready

            // ---- conv2 MFMA ----
            {
                bf16x8 aw[18];
                #pragma unroll
                for (int kt = 0; kt < 18; ++kt)
                    aw[kt] = *(const bf16x8*)(af2 + ((size_t)(mt*18 + kt)*64 + l)*8);
                f32x4 acc0 = {0.f,0.f,0.f,0.f}, acc1 = {0.f,0.f,0.f,0.f};
                #pragma unroll
                for (int kt = 0; kt < 18; ++kt) {
                    const int tap = kt >> 1;
                    const int dB = ((tap/3 - 1)*9 + (tap%3 - 1))*16;
                    const int cb = ((kt & 1)*4 + lhi)*1296;
                    bf16x8 bb0 = *(const bf16x8*)(act1 + cb + paA*16 + dB);
                    bf16x8 bb1 = *(const bf16x8*)(act1 + cb + paB*16 + dB);
                    acc0 = MFMA16(aw[kt], bb0, acc0);
                    acc1 = MFMA16(aw[kt], bb1, acc1);
                }
                #pragma unroll
                for (int r = 0; r < 4; ++r) {
                    v0[r] = acc0[r] + bia2[r] + tval * stabA2[r];
                    v1[r] = acc1[r] + bia2[r] + tval * stabB2[r];
                }
            }
            {
                float s0=0.f,q0=0.f,s1=0.f,q1=0.f;
                if (vA) { s0 += v0[0]+v0[1]; q0 += v0[0]*v0[0]+v0[1]*v0[1];
                          s1 += v0[2]+v0[3]; q1 += v0[2]*v0[2]+v0[3]*v0[3]; }
                if (vB) { s0 += v1[0]+v1[1]; q0 += v1[0]*v1[0]+v1[1]*v1[1];
                          s1 += v1[2]+v1[3]; q1 += v1[2]*v1[2]+v1[3]*v1[3]; }
                #pragma unroll
                for (int off = 1; off < 16; off <<= 1) {
                    s0 += __shfl_xor(s0, off); q0 += __shfl_xor(q0, off);
                    s1 += __shfl_xor(s1, off); q1 += __shfl_xor(q1, off);
                }
                if (llo == 0) {
                    float* gp = gnred + w*16 + lhi*4;
                    gp[0]=s0; gp[1]=q0; gp[2]=s1; gp[3]=q1;
                }
            }
            __syncthreads();   // S4: gnred ready
            {
                const int gb = mt*32 + lhi*4;
                const float sg0 = gnred[gb]   + gnred[gb+16];
                const float qg0 = gnred[gb+1] + gnred[gb+17];
                const float sg1 = gnred[gb+2] + gnred[gb+18];
                const float qg1 = gnred[gb+3] + gnred[gb+19];
                const float m0 = sg0*(1.f/98.f);
                const float r0 = rsqrtf(qg0*(1.f/98.f) - m0*m0 + 1e-5f);
                const float m1 = sg1*(1.f/98.f);
                const float r1 = rsqrtf(qg1*(1.f/98.f) - m1*m1 + 1e-5f);
                short* kd = kbuf + stage*KSTRS;
                const int gA = oc0 >> 1;
                if (vA) {
                    kd[gA*SGRP + pxA]          = (short)cvtpk((v0[0]-m0)*r0*gwC[0]+gbC[0], 0.f);
                    kd[gA*SGRP + 49 + pxA]     = (short)cvtpk((v0[1]-m0)*r0*gwC[1]+gbC[1], 0.f);
                    kd[(gA+1)*SGRP + pxA]      = (short)cvtpk((v0[2]-m1)*r1*gwC[2]+gbC[2], 0.f);
                    kd[(gA+1)*SGRP + 49 + pxA] = (short)cvtpk((v0[3]-m1)*r1*gwC[3]+gbC[3], 0.f);
                }
                if (vB) {
                    kd[gA*SGRP + pxB]          = (short)cvtpk((v1[0]-m0)*r0*gwC[0]+gbC[0], 0.f);
                    kd[gA*SGRP + 49 + pxB]     = (short)cvtpk((v1[1]-m0)*r0*gwC[1]+gbC[1], 0.f);
                    kd[(gA+1)*SGRP + pxB]      = (short)cvtpk((v1[2]-m1)*r1*gwC[2]+gbC[2], 0.f);
                    kd[(gA+1)*SGRP + 49 + pxB] = (short)cvtpk((v1[3]-m1)*r1*gwC[3]+gbC[3], 0.f);
                }
            }
            __syncthreads();   // S5: k ready

            if (stage == 5) {
                float* Yg = y_l + g16*SGRP;
                const short* Kg = kbuf + g16*SGRP;
                const int e0 = 4*sub;
                {
                    f32x4 v = *(const f32x4*)(Yg + e0);
                    v += B0  * ld_k4(Kg + 0*KSTRS + e0);
                    v += B2c * ld_k4(Kg + 2*KSTRS + e0);
                    v += B3c * ld_k4(Kg + 3*KSTRS + e0);
                    v += B4c * ld_k4(Kg + 4*KSTRS + e0);
                    v += B5c * ld_k4(Kg + 5*KSTRS + e0);
                    *(f32x4*)(Yg + e0) = v;
                }
                if (sub < 8) {
                    const int e1 = 64 + 4*sub;
                    f32x4 v = *(const f32x4*)(Yg + e1);
                    v += B0  * ld_k4(Kg + 0*KSTRS + e1);
                    v += B2c * ld_k4(Kg + 2*KSTRS + e1);
                    v += B3c * ld_k4(Kg + 3*KSTRS + e1);
                    v += B4c * ld_k4(Kg + 4*KSTRS + e1);
                    v += B5c * ld_k4(Kg + 5*KSTRS + e1);
                    *(f32x4*)(Yg + e1) = v;
                } else if (sub == 8) {
                    #pragma unroll
                    for (int j2 = 0; j2 < 2; ++j2) {
                        const int e = 96 + j2;
                        float v = Yg[e];
                        v = fmaf(B0,  bf2f(Kg[0*KSTRS+e]), v);
                        v = fmaf(B2c, bf2f(Kg[2*KSTRS+e]), v);
                        v = fmaf(B3c, bf2f(Kg[3*KSTRS+e]), v);
                        v = fmaf(B4c, bf2f(Kg[4*KSTRS+e]), v);
                        v = fmaf(B5c, bf2f(Kg[5*KSTRS+e]), v);
                        Yg[e] = v;
                    }
                }
                __syncthreads();   // S6: y updated
            }
        }
    }

    // ---- head: GN(g3)+ReLU -> spatial mean -> linear ----
    {
        float s = 0.f, q = 0.f;
        const float* Yg = y_l + g16*SGRP;
        for (int e = sub; e < 98; e += 16) {
            float v = Yg[e];
            s += v; q += v*v;
        }
        s += __shfl_xor(s,1); q += __shfl_xor(q,1);
        s += __shfl_xor(s,2); q += __shfl_xor(q,2);
        s += __shfl_xor(s,4); q += __shfl_xor(q,4);
        s += __shfl_xor(s,8); q += __shfl_xor(q,8);
        if (sub == 0) {
            float m = s * (1.f/98.f);
            float var = q * (1.f/98.f) - m*m;
            s_mean[g16] = m; s_rstd[g16] = rsqrtf(var + 1e-5f);
        }
    }
    __syncthreads();
    if (t < 64) {
        const int ch = t, g = ch >> 1;
        const float m = s_mean[g], r = s_rstd[g];
        const float ww = g3w[ch], bb = g3b[ch];
        const float* Yc = y_l + g*SGRP + (ch & 1)*49;
        float sum = 0.f;
        for (int p = 0; p < 49; ++p) {
            float v = (Yc[p] - m)*r*ww + bb;
            sum += fmaxf(v, 0.f);
        }
        s_cm[ch] = sum * (1.f/49.f);
    }
    __syncthreads();
    if (t < 10) {
        float a = linb[t];
        for (int c = 0; c < 64; ++c) a = fmaf(s_cm[c], linw[t*64 + c], a);
        out[b*10 + t] = a;
    }
}

// ---------------------------------------------------------------------------
// Host launch
// ---------------------------------------------------------------------------
extern "C" void kernel_launch(void* const* d_in, const int* in_sizes, int n_in,
                              void* d_out, int out_size, void* d_ws, size_t ws_size,
                              hipStream_t stream)
{
    const float* x      = (const float*)d_in[0];
    const float* c1_w   = (const float*)d_in[1];
    const float* c1_b   = (const float*)d_in[2];
    const float* g1_w   = (const float*)d_in[3];
    const float* g1_b   = (const float*)d_in[4];
    const float* c2_w   = (const float*)d_in[5];
    const float* c2_b   = (const float*)d_in[6];
    const float* g2_w   = (const float*)d_in[7];
    const float* g2_b   = (const float*)d_in[8];
    const float* c3_w   = (const float*)d_in[9];
    const float* c3_b   = (const float*)d_in[10];
    const float* oa_w   = (const float*)d_in[11];
    const float* oa_b   = (const float*)d_in[12];
    const float* occ1_w = (const float*)d_in[13];
    const float* occ1_b = (const float*)d_in[14];
    const float* ob_w   = (const float*)d_in[15];
    const float* ob_b   = (const float*)d_in[16];
    const float* occ2_w = (const float*)d_in[17];
    const float* occ2_b = (const float*)d_in[18];
    const float* oc_w   = (const float*)d_in[19];
    const float* oc_b   = (const float*)d_in[20];
    const float* g3_w   = (const float*)d_in[21];
    const float* g3_b   = (const float*)d_in[22];
    const float* lin_w  = (const float*)d_in[23];
    const float* lin_b  = (const float*)d_in[24];
    float* out = (float*)d_out;

    float* ws = (float*)d_ws;
    size_t off = 0;
    float* y     = ws + off; off += 802816;
    float* stab1 = ws + off; off += 3136;
    float* stab2 = ws + off; off += 3136;
    short* af1   = (short*)(ws + off); off += 18432;    // 36864 shorts
    short* af2   = (short*)(ws + off); off += 18432;
    short* afc1  = (short*)(ws + off); off += 1024;     // 2048 shorts
    short* afc2  = (short*)(ws + off); off += 32768;    // 65536 shorts
    short* afc3  = (short*)(ws + off); off += 32768;
    short* h1pad = (short*)(ws + off); off += 8396800;  // 256*65600 shorts
    short* h2pad = (short*)(ws + off); off += 2367488;  // 256*18496 shorts

    // prep (weights constant per launch)
    prep_afrag_kernel<<<dim3(144, 2), 256, 0, stream>>>(occ1_w, occ2_w, af1, af2);
    prep_stab_kernel<<<dim3(13, 2), 256, 0, stream>>>(occ1_w, occ2_w, stab1, stab2);
    prep_c1frag_kernel<<<8, 256, 0, stream>>>(c1_w, afc1);
    prep_c23frag_kernel<<<dim3(256, 2), 256, 0, stream>>>(c2_w, c3_w, afc2, afc3);

    // preamble CNN (fused, per-image MFMA)
    conv1_fused<<<B, 512, 0, stream>>>(x, afc1, c1_b, g1_w, g1_b, h1pad);
    conv2_fused<<<B, 512, CONV2_LDS, stream>>>(h1pad, afc2, c2_b, g2_w, g2_b, h2pad);
    conv3_mfma<<<B, 512, 0, stream>>>(h2pad, afc3, c3_b, y);

    // full ODE + head, one launch (75.5 KB LDS -> 2 blocks/CU at <=128 VGPR)
    ode_head<<<B, 512, ODE_LDS, stream>>>(y, af1, af2, stab1, stab2,
        occ1_b, occ2_b, oa_w, oa_b, ob_w, ob_b, oc_w, oc_b,
        g3_w, g3_b, lin_w, lin_b, out);
}